// Round 12
// baseline (2208.960 us; speedup 1.0000x reference)
//
#include <hip/hip_runtime.h>
#include <math.h>

// Problem constants
static constexpr int Bc = 8;
static constexpr int Sc = 512;
static constexpr int Hc = 768;
static constexpr int NHc = 12;
static constexpr int Lc = 12;
static constexpr int Fc = 3072;
static constexpr int DHc = 64;
static constexpr int NTOK = Bc * Sc;      // 4096
static constexpr int QKVN = 3 * Hc;       // 2304

// all-layer transposed-weight block offsets (fp16 elements)
static constexpr size_t W_QKV_OFF = 0;                    // [2304][768]
static constexpr size_t W_AO_OFF  = 1769472;              // [768][768]
static constexpr size_t W_I_OFF   = 2359296;              // [3072][768]
static constexpr size_t W_IO_OFF  = 4718592;              // [768][3072]
static constexpr size_t LW        = 7077888;              // per-layer total

typedef _Float16 h16x8 __attribute__((ext_vector_type(8)));
typedef float f32x4 __attribute__((ext_vector_type(4)));
typedef unsigned short us4 __attribute__((ext_vector_type(4)));
typedef unsigned short us8 __attribute__((ext_vector_type(8)));
typedef unsigned int u32x4 __attribute__((ext_vector_type(4)));

__device__ __forceinline__ unsigned short f2h(float f) {
    _Float16 h = (_Float16)f;                    // v_cvt_f16_f32, RTE
    return __builtin_bit_cast(unsigned short, h);
}
__device__ __forceinline__ float h2f(unsigned short u) {
    return (float)__builtin_bit_cast(_Float16, u);
}

// exact-erf gelu via A&S 7.1.26 rational approx (max |err(erf)| = 1.5e-7):
// far cheaper than libm erff (~10 VALU + exp + rcp vs 30+).
__device__ __forceinline__ float gelu_fast(float v) {
    float z = v * 0.70710678118654752f;
    float az = fabsf(z);
    float t = __builtin_amdgcn_rcpf(fmaf(0.3275911f, az, 1.0f));
    float poly = fmaf(fmaf(fmaf(fmaf(1.061405429f, t, -1.453152027f), t,
                    1.421413741f), t, -0.284496736f), t, 0.254829592f) * t;
    float erf = 1.0f - poly * __expf(-az * az);
    erf = (z < 0.f) ? -erf : erf;
    return 0.5f * v * (1.0f + erf);
}

#define AS1 __attribute__((address_space(1)))
#define AS3 __attribute__((address_space(3)))
__device__ __forceinline__ void gld_lds16(const void* g, void* l) {
    __builtin_amdgcn_global_load_lds((const AS1 void*)g, (AS3 void*)l, 16, 0, 0);
}

// ---------------------------------------------------------------------------
// ALL-layer weight prep (round-6 tile version: best measured, ~124 us).
// 64x64 transpose tiles, float4 reads, us8 writes.
// blockIdx.y = layer; blockIdx.x: 1728 tiles + 9 bias blocks.
// ---------------------------------------------------------------------------
__global__ __launch_bounds__(256) void prep_kernel(
    const float* __restrict__ Wq, const float* __restrict__ Wk,
    const float* __restrict__ Wv, const float* __restrict__ Wao,
    const float* __restrict__ Wi, const float* __restrict__ Wio,
    const float* __restrict__ bq, const float* __restrict__ bk,
    const float* __restrict__ bv, unsigned short* __restrict__ WALL,
    float* __restrict__ BALL)
{
    int t = blockIdx.x, l = blockIdx.y;
    int tid = threadIdx.x;

    if (t >= 1728) {   // bias concat: 9 blocks x 256 = 2304
        int idx = (t - 1728) * 256 + tid;
        float v = (idx < 768) ? bq[l * Hc + idx]
                : (idx < 1536) ? bk[l * Hc + idx - 768]
                               : bv[l * Hc + idx - 1536];
        BALL[(size_t)l * QKVN + idx] = v;
        return;
    }

    const float* src;
    unsigned short* dst;
    int K, N, ntn, local;
    if (t < 576) {                       // Wq,Wk,Wv,Wao: 144 tiles each
        int mat = t / 144; local = t % 144;
        K = 768; N = 768; ntn = 12;
        src = (mat == 0 ? Wq : mat == 1 ? Wk : mat == 2 ? Wv : Wao) + (size_t)l * 589824;
        dst = WALL + (size_t)l * LW + (mat < 3 ? (size_t)mat * 589824 : W_AO_OFF);
    } else if (t < 1152) {               // Wi: 576 tiles
        local = t - 576; K = 768; N = 3072; ntn = 48;
        src = Wi + (size_t)l * 2359296;
        dst = WALL + (size_t)l * LW + W_I_OFF;
    } else {                             // Wio: 576 tiles
        local = t - 1152; K = 3072; N = 768; ntn = 12;
        src = Wio + (size_t)l * 2359296;
        dst = WALL + (size_t)l * LW + W_IO_OFF;
    }
    int n0 = (local % ntn) * 64, k0 = (local / ntn) * 64;

    __shared__ float tl[64][65];
    int tx = tid & 15, ty = tid >> 4;    // tx: 4-float col group, ty: row
#pragma unroll
    for (int j = 0; j < 4; j++) {
        int k = ty + j * 16;
        float4 v = *(const float4*)(src + (size_t)(k0 + k) * N + n0 + tx * 4);
        tl[k][tx * 4 + 0] = v.x; tl[k][tx * 4 + 1] = v.y;
        tl[k][tx * 4 + 2] = v.z; tl[k][tx * 4 + 3] = v.w;
    }
    __syncthreads();
#pragma unroll
    for (int q = 0; q < 2; q++) {
        int chunk = q * 256 + tid;
        int row = chunk >> 3, c = chunk & 7;
        us8 o;
#pragma unroll
        for (int j = 0; j < 8; j++) o[j] = f2h(tl[c * 8 + j][row]);
        *(us8*)(dst + (size_t)(n0 + row) * K + k0 + c * 8) = o;
    }
}

// ---------------------------------------------------------------------------
// 192-thread LN reduction helper: thread i owns elems 4i..4i+3 of a 768-row.
// ---------------------------------------------------------------------------
__device__ __forceinline__ void ln_stats192(float4 v, float& mean, float& rstd) {
    float s = v.x + v.y + v.z + v.w;
    float s2 = v.x * v.x + v.y * v.y + v.z * v.z + v.w * v.w;
#pragma unroll
    for (int o = 32; o > 0; o >>= 1) { s += __shfl_xor(s, o); s2 += __shfl_xor(s2, o); }
    __shared__ float red[6];
    int lane = threadIdx.x & 63, wid = threadIdx.x >> 6;
    if (lane == 0) { red[wid] = s; red[3 + wid] = s2; }
    __syncthreads();
    float ts  = red[0] + red[1] + red[2];
    float ts2 = red[3] + red[4] + red[5];
    mean = ts * (1.0f / Hc);
    float var = ts2 * (1.0f / Hc) - mean * mean;
    rstd = rsqrtf(var + 1e-12f);
}

// ---------------------------------------------------------------------------
// Embedding + LayerNorm -> fp32 X and fp16 X  (192 threads, float4)
// ---------------------------------------------------------------------------
__global__ __launch_bounds__(192) void embed_ln_kernel(
    const int* __restrict__ ids, const int* __restrict__ seg,
    const float* __restrict__ tok, const float* __restrict__ typ,
    const float* __restrict__ pos, const float* __restrict__ g,
    const float* __restrict__ b, float* __restrict__ outf,
    unsigned short* __restrict__ outb)
{
    int t = blockIdx.x;
    int si = t % Sc;
    int id = ids[t], sg = seg[t];
    int i = threadIdx.x;

    float4 tv = *(const float4*)(tok + (size_t)id * Hc + 4 * i);
    float4 yv = *(const float4*)(typ + (size_t)sg * Hc + 4 * i);
    float4 pv = *(const float4*)(pos + (size_t)si * Hc + 4 * i);
    float4 v = make_float4(tv.x + yv.x + pv.x, tv.y + yv.y + pv.y,
                           tv.z + yv.z + pv.z, tv.w + yv.w + pv.w);
    float mean, rstd;
    ln_stats192(v, mean, rstd);

    float4 gv = *(const float4*)(g + 4 * i);
    float4 bv = *(const float4*)(b + 4 * i);
    float4 o = make_float4(gv.x * (v.x - mean) * rstd + bv.x,
                           gv.y * (v.y - mean) * rstd + bv.y,
                           gv.z * (v.z - mean) * rstd + bv.z,
                           gv.w * (v.w - mean) * rstd + bv.w);
    *(float4*)(outf + (size_t)t * Hc + 4 * i) = o;
    us4 ob; ob[0] = f2h(o.x); ob[1] = f2h(o.y); ob[2] = f2h(o.z); ob[3] = f2h(o.w);
    *(us4*)(outb + (size_t)t * Hc + 4 * i) = ob;
}

// ---------------------------------------------------------------------------
// (fp16 partial0 + fp16 partial1 + fp32 residual) -> LN -> fp32 + fp16
// ---------------------------------------------------------------------------
__global__ __launch_bounds__(192) void add_ln2h_kernel(
    const unsigned short* __restrict__ t0, const unsigned short* __restrict__ t1,
    const float* __restrict__ res, const float* __restrict__ g,
    const float* __restrict__ b, float* __restrict__ outf,
    unsigned short* __restrict__ outb)
{
    int t = blockIdx.x;
    int i = threadIdx.x;
    us4 a = *(const us4*)(t0 + (size_t)t * Hc + 4 * i);
    us4 c = *(const us4*)(t1 + (size_t)t * Hc + 4 * i);
    float4 r = *(const float4*)(res + (size_t)t * Hc + 4 * i);
    float4 v = make_float4(h2f(a[0]) + h2f(c[0]) + r.x,
                           h2f(a[1]) + h2f(c[1]) + r.y,
                           h2f(a[2]) + h2f(c[2]) + r.z,
                           h2f(a[3]) + h2f(c[3]) + r.w);
    float mean, rstd;
    ln_stats192(v, mean, rstd);

    float4 gv = *(const float4*)(g + 4 * i);
    float4 bv = *(const float4*)(b + 4 * i);
    float4 o = make_float4(gv.x * (v.x - mean) * rstd + bv.x,
                           gv.y * (v.y - mean) * rstd + bv.y,
                           gv.z * (v.z - mean) * rstd + bv.z,
                           gv.w * (v.w - mean) * rstd + bv.w);
    *(float4*)(outf + (size_t)t * Hc + 4 * i) = o;
    us4 ob; ob[0] = f2h(o.x); ob[1] = f2h(o.y); ob[2] = f2h(o.z); ob[3] = f2h(o.w);
    *(us4*)(outb + (size_t)t * Hc + 4 * i) = ob;
}

// ---------------------------------------------------------------------------
// FP16 MFMA GEMM (single-buffer m97 structure, ~4 blocks/CU) + XCD swizzle.
// OUT: 1 = gelu+fp16, 2 = fp16, 3 = QKV mode (col<1536 -> Cb ld 1536,
//      col>=1536 -> V transposed to VTp[B][NH][DH][S]),
//      4 = fp16 split-K partial to Cb + z*M*N (bias added on z==0 only)
// ---------------------------------------------------------------------------
template <int OUT>
__global__ __launch_bounds__(256) void gemm_mfma(
    const unsigned short* __restrict__ A,   // [M][K] fp16
    const unsigned short* __restrict__ Bt,  // [N][K] fp16
    const float* __restrict__ bias,         // [N]
    unsigned short* __restrict__ Cb,
    unsigned short* __restrict__ VTp,
    int M, int N, int K, int kspan)
{
    __shared__ __align__(16) unsigned short As[128 * 64];
    __shared__ __align__(16) unsigned short Bs[128 * 64];

    int tid = threadIdx.x;
    int l = tid & 63, w = tid >> 6;

    // XCD-aware swizzle (bijective: all grids here have nwg % 8 == 0)
    int nbx = gridDim.x;
    int nwg = nbx * gridDim.y;
    int bid = blockIdx.y * nbx + blockIdx.x;
    if ((nwg & 7) == 0) {
        int cpx = nwg >> 3;
        bid = (bid & 7) * cpx + (bid >> 3);
    }
    int m0 = (bid % nbx) * 128, n0 = (bid / nbx) * 128;

    int lr = l & 15;
    int kg = l >> 4;
    int wr = (w >> 1) * 64, wc = (w & 1) * 64;
    int lx = lr & 7;
    int kbeg = blockIdx.z * kspan;

    f32x4 acc[4][4] = {};

    for (int k0 = kbeg; k0 < kbeg + kspan; k0 += 64) {
#pragma unroll
        for (int p = 0; p < 4; p++) {
            int i = p * 256 + w * 64 + l;
            int row = i >> 3;
            int slot = (i & 7) ^ (row & 7);
            const unsigned short* ga = A + (size_t)(m0 + row) * K + k0 + slot * 8;
            const unsigned short* gb = Bt + (size_t)(n0 + row) * K + k0 + slot * 8;
            unsigned short* la = As + (size_t)(p * 256 + w * 64) * 8;
            unsigned short* lb = Bs + (size_t)(p * 256 + w * 64) * 8;
            gld_lds16(ga, la);
            gld_lds16(gb, lb);
        }
        asm volatile("s_waitcnt vmcnt(0)" ::: "memory");
        __syncthreads();

#pragma unroll
        for (int kh = 0; kh < 2; kh++) {
            h16x8 av[4], bv[4];
#pragma unroll
            for (int f = 0; f < 4; f++) {
                int sl = (kh * 4 + kg) ^ lx;
                av[f] = *(const h16x8*)(As + (wr + f * 16 + lr) * 64 + sl * 8);
                bv[f] = *(const h16x8*)(Bs + (wc + f * 16 + lr) * 64 + sl * 8);
            }
#pragma unroll
            for (int i = 0; i < 4; i++)
#pragma unroll
                for (int j = 0; j < 4; j++)
                    acc[i][j] = __builtin_amdgcn_mfma_f32_16x16x32_f16(
                        av[i], bv[j], acc[i][j], 0, 0, 0);
        }
        __syncthreads();
    }

#pragma unroll
    for (int i = 0; i < 4; i++) {
        int rbase = m0 + wr + i * 16 + kg * 4;
#pragma unroll
        for (int j = 0; j < 4; j++) {
            int col = n0 + wc + j * 16 + lr;
            float bcol = (OUT == 4 && blockIdx.z > 0) ? 0.f : bias[col];
            if (OUT == 3 && col >= 1536) {
                // V columns -> transposed store VT[b][h][d][s]
                int vcol = col - 1536;
                int hh = vcol >> 6, d = vcol & 63;
                int bbb = rbase >> 9, s0 = rbase & 511;
                us4 ob;
#pragma unroll
                for (int r = 0; r < 4; r++) ob[r] = f2h(acc[i][j][r] + bcol);
                *(us4*)(VTp + ((((size_t)bbb * NHc + hh) * DHc + d) << 9) + s0) = ob;
            } else if (OUT == 4) {
                unsigned short* op = Cb + (size_t)blockIdx.z * M * N;
#pragma unroll
                for (int r = 0; r < 4; r++)
                    op[(size_t)(rbase + r) * N + col] = f2h(acc[i][j][r] + bcol);
            } else {
                int ldc = (OUT == 3) ? 1536 : N;
#pragma unroll
                for (int r = 0; r < 4; r++) {
                    float v = acc[i][j][r] + bcol;
                    if (OUT == 1) v = gelu_fast(v);
                    Cb[(size_t)(rbase + r) * ldc + col] = f2h(v);
                }
            }
        }
    }
}

// ---------------------------------------------------------------------------
// MFMA flash attention (round-9/10 KVBLK=64 version + T13 defer-max).
// fp16 fragments, fp32 softmax/accum. 16.5 KB LDS -> 8 blocks/CU.
// QK fp16 [NTOK][1536] (Q at 0, K at 768); VT fp16 [B][NH][DH][S].
// Out ctx fp16 [NTOK][768].
// S^T = mfma(K, Q) -> lane owns q-col c = l&15, kv rows 16f+4g+r.
// O^T = mfma(Vt, P^T) -> lane owns O[q=c][d=16fm+4g+r].
// ---------------------------------------------------------------------------
__global__ __launch_bounds__(256) void attn_mfma(
    const unsigned short* __restrict__ QK, const unsigned short* __restrict__ VT,
    const float* __restrict__ mask, unsigned short* __restrict__ O)
{
    const int LD = 1536;
    __shared__ __align__(16) unsigned short Ks[64 * 64];
    __shared__ __align__(16) unsigned short Vt[64 * 64];   // [d][kv], swizzled
    __shared__ float Ml[64];

    int tid = threadIdx.x;
    int l = tid & 63, w = tid >> 6;
    int g = l >> 4, c = l & 15;
    int q0 = blockIdx.x * 64;
    int h = blockIdx.y, bb = blockIdx.z;

    // Q fragment (B-operand of S^T mfma): Q[q=c][d = 32*kh + 8g + j]
    const size_t rowQ = (size_t)(bb * Sc + q0 + w * 16 + c) * LD + h * DHc;
    h16x8 qv[2];
    qv[0] = *(const h16x8*)(QK + rowQ + 8 * g);
    qv[1] = *(const h16x8*)(QK + rowQ + 32 + 8 * g);

    float m_run = -1e30f, l_run = 0.f;
    f32x4 acc_o[4] = {};
    const float scale = 0.125f;

    for (int kt = 0; kt < Sc; kt += 64) {
        // ---- stage K tile (swizzled source -> linear LDS) ----
        const unsigned short* Kgb = QK + (size_t)(bb * Sc + kt) * LD + Hc + h * DHc;
#pragma unroll
        for (int p = 0; p < 2; p++) {
            int i = p * 256 + tid;
            int row = i >> 3;
            int slot = (i & 7) ^ (row & 7);
            gld_lds16(Kgb + (size_t)row * LD + slot * 8, Ks + (size_t)(p * 256 + w * 64) * 8);
        }
        // ---- stage V^T tile from VT[b][h][d][s] (row d, 64 s each) ----
        const unsigned short* Vg = VT + (((size_t)bb * NHc + h) * DHc << 9) + kt;
#pragma unroll
        for (int p = 0; p < 2; p++) {
            int i = p * 256 + tid;
            int row = i >> 3;
            int slot = (i & 7) ^ (row & 7);
            gld_lds16(Vg + ((size_t)row << 9) + slot * 8, Vt + (size_t)(p * 256 + w * 64) * 8);
        }
        if (tid < 64) Ml[tid] = (1.0f - mask[bb * Sc + kt + tid]) * -10000.0f;
        asm volatile("s_waitcnt vmcnt(0)" ::: "memory");
        __syncthreads();

        // ---- S^T = K @ Q^T : rows kv (4 frags), cols q ----
        f32x4 s[4] = {};
#pragma unroll
        for (int kh = 0; kh < 2; kh++) {
#pragma unroll
            for (int f = 0; f < 4; f++) {
                int row = f * 16 + c;
                h16x8 av = *(const h16x8*)(Ks + row * 64 + (((kh * 4 + g) ^ (row & 7)) * 8));
                s[f] = __builtin_amdgcn_mfma_f32_16x16x32_f16(av, qv[kh], s[f], 0, 0, 0);
            }
        }

        // ---- softmax (per q = c, values spread over g-groups) ----
        f32x4 mv[4];
#pragma unroll
        for (int f = 0; f < 4; f++) mv[f] = *(const f32x4*)&Ml[f * 16 + 4 * g];
        float mx = -1e30f;
#pragma unroll
        for (int f = 0; f < 4; f++)
#pragma unroll
            for (int r = 0; r < 4; r++) {
                float sv = s[f][r] * scale + mv[f][r];
                s[f][r] = sv;
                mx = fmaxf(mx, sv);
            }
        mx = fmaxf(mx, __shfl_xor(mx, 16));
        mx = fmaxf(mx, __shfl_xor(mx, 32));
        if (!__all(mx - m_run <= 8.0f)) {     // T13: skip rescale if max stable
            float mn = fmaxf(m_run, mx);
            float fs = __expf(m_run - mn);
            m_run = mn;
            l_run *= fs;
#pragma unroll
            for (int fm = 0; fm < 4; fm++)
#pragma unroll
                for (int r = 0; r < 4; r++) acc_o[fm][r] *= fs;
        }
        float ps = 0.f;
        f32x4 p[4];
#pragma unroll
        for (int f = 0; f < 4; f++)
#pragma unroll
            for (int r = 0; r < 4; r++) {
                float pv = __expf(s[f][r] - m_run);
                p[f][r] = pv;
                ps += pv;
            }
        ps += __shfl_xor(ps, 16);
        ps += __shfl_xor(ps, 32);
        l_run += ps;

        // ---- pack P to fp16 pairs ----
        unsigned pk[4][2];
#pragma unroll
        for (int f = 0; f < 4; f++)
#pragma unroll
            for (int rp = 0; rp < 2; rp++)
                pk[f][rp] = ((unsigned)f2h(p[f][2 * rp + 1]) << 16) | f2h(p[f][2 * rp]);

        // ---- PV: O^T += Vt @ P^T ----
        // dest lane (g,c) word t needs P[q=c][kv=32kh+8g+2t+{0,1}] =
        // pk[2kh + (g>>1)][t&1] from lane g_src = 2(g&1)+(t>>1);
        // f-select AFTER shuffle (uses dest g).
#pragma unroll
        for (int kh = 0; kh < 2; kh++) {
            u32x4 bw;
#pragma unroll
            for (int t = 0; t < 4; t++) {
                int srcl = (2 * ((l >> 4) & 1) + (t >> 1)) * 16 + c;
                unsigned lo = __shfl(pk[2 * kh][t & 1], srcl);
                unsigned hi = __shfl(pk[2 * kh + 1][t & 1], srcl);
                bw[t] = (g & 2) ? hi : lo;
            }
            h16x8 bfrag = __builtin_bit_cast(h16x8, bw);
#pragma unroll
            for (int fm = 0; fm < 4; fm++) {
                int row = fm * 16 + c;
                h16x8 av = *(const h16x8*)(Vt + row * 64 + (((kh * 4 + g) ^ (row & 7)) * 8));
                acc_o[fm] = __builtin_amdgcn_mfma_f32_16x16x32_f16(av, bfrag, acc_o[fm], 0, 0, 0);
            }
        }
        __syncthreads();
    }

    // ---- epilogue: O[q=c][d = 16fm + 4g + r] / l ----
    float rl = 1.0f / l_run;
    size_t tokrow = (size_t)(bb * Sc + q0 + w * 16 + c) * Hc + h * DHc;
#pragma unroll
    for (int fm = 0; fm < 4; fm++) {
        us4 ob;
#pragma unroll
        for (int r = 0; r < 4; r++) ob[r] = f2h(acc_o[fm][r] * rl);
        *(us4*)(O + tokrow + fm * 16 + 4 * g) = ob;
    }
}

// ---------------------------------------------------------------------------
extern "C" void kernel_launch(void* const* d_in, const int* in_sizes, int n_in,
                              void* d_out, int out_size, void* d_ws, size_t ws_size,
                              hipStream_t stream)
{
    const int*   input_ids      = (const int*)  d_in[0];
    const int*   segment_ids    = (const int*)  d_in[1];
    const float* attention_mask = (const float*)d_in[2];
    const float* tok_emb = (const float*)d_in[3];
    const float* pos_emb = (const float*)d_in[4];
    const float* type_emb= (const float*)d_in[5];
    const float* emb_g   = (const float*)d_in[6];
    const float* emb_b   = (const float*)d_in[7];
    const float* Wq  = (const float*)d_in[8];  const float* bq  = (const float*)d_in[9];
    const float* Wk  = (const float*)d_in[10]; const float* bk  = (const float*)d_in[11];
    const float* Wv  = (const float*)d_in[12]; const float* bv  = (const float*)d_in[13];
    const float* Wao = (const float*)d_in[14]; const float* bao = (const float*)d_in[15];
    const float* ln1_g = (const float*)d_in[16]; const float* ln1_b = (const float*)d_in[17];
    const float* Wi  = (const float*)d_in[18]; const float* bi  = (const float*)d_in[19];
    const float* Wio = (const float*)d_in[20]; const float* bio = (const float*)d_in[21];
    const float* ln2_g = (const float*)d_in[22]; const float* ln2_b = (const float*)d_in[23];

    float* out = (float*)d_out;

    const size_t NT = (size_t)NTOK * Hc;
    float* Xf   = (float*)d_ws;
    float* XAf  = Xf + NT;
    float* BALL = XAf + NT;                                  // 12*2304 fp32
    unsigned short* QKb = (unsigned short*)(BALL + (size_t)Lc * QKVN);
    unsigned short* VT  = QKb + (size_t)NTOK * 1536;         // [B][NH][DH][S]
    unsigned short* Xb  = VT + NT;
    unsigned short* XAb = Xb + NT;
    unsigned short* Cb  = XAb + NT;
    unsigned short* Tp  = Cb + NT;                           // 2 x NT fp16 split-K partials
    unsigned short* Hb  = Tp + 2 * NT;                       // [NTOK][3072]
    unsigned short* WALL = Hb + (size_t)NTOK * Fc;           // 12 * LW fp16

    // ---- one-shot prep: all weight transposes + bias concat ----
    prep_kernel<<<dim3(1737, Lc), 256, 0, stream>>>(Wq, Wk, Wv, Wao, Wi, Wio,
                                                    bq, bk, bv, WALL, BALL);

    embed_ln_kernel<<<NTOK, 192, 0, stream>>>(input_ids, segment_ids, tok_emb,
                                              type_emb, pos_emb, emb_g, emb_b, Xf, Xb);

    dim3 gQKV(NTOK / 128, QKVN / 128);      // 32 x 18
    dim3 gF(NTOK / 128, Fc / 128);          // 32 x 24
    dim3 gH2(NTOK / 128, Hc / 128, 2);      // 32 x 6 x 2 (split-K AO/FFN2)
    dim3 gA(Sc / 64, NHc, Bc);              // 8 x 12 x 8

    for (int l = 0; l < Lc; l++) {
        const unsigned short* WqkvT = WALL + (size_t)l * LW + W_QKV_OFF;
        const unsigned short* WaoT  = WALL + (size_t)l * LW + W_AO_OFF;
        const unsigned short* WiT   = WALL + (size_t)l * LW + W_I_OFF;
        const unsigned short* WioT  = WALL + (size_t)l * LW + W_IO_OFF;
        const float* bqkv = BALL + (size_t)l * QKVN;

        // fused QKV GEMM -> QKb (Q,K) + VT (V transposed)
        gemm_mfma<3><<<gQKV, 256, 0, stream>>>(Xb, WqkvT, bqkv, QKb, VT,
                                               NTOK, QKVN, Hc, Hc);
        attn_mfma<<<gA, 256, 0, stream>>>(QKb, VT, attention_mask, Cb);

        // attention-out dense, split-K=2 -> fp16 partials
        gemm_mfma<4><<<gH2, 256, 0, stream>>>(Cb, WaoT, bao + (size_t)l * Hc, Tp,
                                              nullptr, NTOK, Hc, Hc, Hc / 2);
        add_ln2h_kernel<<<NTOK, 192, 0, stream>>>(Tp, Tp + NT, Xf,
                                                  ln1_g + (size_t)l * Hc,
                                                  ln1_b + (size_t)l * Hc, XAf, XAb);

        // FFN1 + gelu -> Hb (fp16)
        gemm_mfma<1><<<gF, 256, 0, stream>>>(XAb, WiT, bi + (size_t)l * Fc, Hb,
                                             nullptr, NTOK, Fc, Hc, Hc);
        // FFN2 split-K=2 -> fp16 partials
        gemm_mfma<4><<<gH2, 256, 0, stream>>>(Hb, WioT, bio + (size_t)l * Hc, Tp,
                                              nullptr, NTOK, Hc, Fc, Fc / 2);
        float* xout = (l == Lc - 1) ? out : Xf;
        add_ln2h_kernel<<<NTOK, 192, 0, stream>>>(Tp, Tp + NT, XAf,
                                                  ln2_g + (size_t)l * Hc,
                                                  ln2_b + (size_t)l * Hc, xout, Xb);
    }
}

// Round 13
// 2031.899 us; speedup vs baseline: 1.0871x; 1.0871x over previous
//
#include <hip/hip_runtime.h>
#include <math.h>

// Problem constants
static constexpr int Bc = 8;
static constexpr int Sc = 512;
static constexpr int Hc = 768;
static constexpr int NHc = 12;
static constexpr int Lc = 12;
static constexpr int Fc = 3072;
static constexpr int DHc = 64;
static constexpr int NTOK = Bc * Sc;      // 4096
static constexpr int QKVN = 3 * Hc;       // 2304

// all-layer transposed-weight block offsets (fp16 elements)
static constexpr size_t W_QKV_OFF = 0;                    // [2304][768]
static constexpr size_t W_AO_OFF  = 1769472;              // [768][768]
static constexpr size_t W_I_OFF   = 2359296;              // [3072][768]
static constexpr size_t W_IO_OFF  = 4718592;              // [768][3072]
static constexpr size_t LW        = 7077888;              // per-layer total

typedef _Float16 h16x8 __attribute__((ext_vector_type(8)));
typedef float f32x4 __attribute__((ext_vector_type(4)));
typedef unsigned short us4 __attribute__((ext_vector_type(4)));
typedef unsigned short us8 __attribute__((ext_vector_type(8)));
typedef unsigned int u32x4 __attribute__((ext_vector_type(4)));

__device__ __forceinline__ unsigned short f2h(float f) {
    _Float16 h = (_Float16)f;                    // v_cvt_f16_f32, RTE
    return __builtin_bit_cast(unsigned short, h);
}
__device__ __forceinline__ float h2f(unsigned short u) {
    return (float)__builtin_bit_cast(_Float16, u);
}

#define AS1 __attribute__((address_space(1)))
#define AS3 __attribute__((address_space(3)))
__device__ __forceinline__ void gld_lds16(const void* g, void* l) {
    __builtin_amdgcn_global_load_lds((const AS1 void*)g, (AS3 void*)l, 16, 0, 0);
}

// ---------------------------------------------------------------------------
// ALL-layer weight prep (tile version: best measured of 3 variants, ~124 us).
// 64x64 transpose tiles, float4 reads, us8 writes.
// blockIdx.y = layer; blockIdx.x: 1728 tiles + 9 bias blocks.
// ---------------------------------------------------------------------------
__global__ __launch_bounds__(256) void prep_kernel(
    const float* __restrict__ Wq, const float* __restrict__ Wk,
    const float* __restrict__ Wv, const float* __restrict__ Wao,
    const float* __restrict__ Wi, const float* __restrict__ Wio,
    const float* __restrict__ bq, const float* __restrict__ bk,
    const float* __restrict__ bv, unsigned short* __restrict__ WALL,
    float* __restrict__ BALL)
{
    int t = blockIdx.x, l = blockIdx.y;
    int tid = threadIdx.x;

    if (t >= 1728) {   // bias concat: 9 blocks x 256 = 2304
        int idx = (t - 1728) * 256 + tid;
        float v = (idx < 768) ? bq[l * Hc + idx]
                : (idx < 1536) ? bk[l * Hc + idx - 768]
                               : bv[l * Hc + idx - 1536];
        BALL[(size_t)l * QKVN + idx] = v;
        return;
    }

    const float* src;
    unsigned short* dst;
    int K, N, ntn, local;
    if (t < 576) {                       // Wq,Wk,Wv,Wao: 144 tiles each
        int mat = t / 144; local = t % 144;
        K = 768; N = 768; ntn = 12;
        src = (mat == 0 ? Wq : mat == 1 ? Wk : mat == 2 ? Wv : Wao) + (size_t)l * 589824;
        dst = WALL + (size_t)l * LW + (mat < 3 ? (size_t)mat * 589824 : W_AO_OFF);
    } else if (t < 1152) {               // Wi: 576 tiles
        local = t - 576; K = 768; N = 3072; ntn = 48;
        src = Wi + (size_t)l * 2359296;
        dst = WALL + (size_t)l * LW + W_I_OFF;
    } else {                             // Wio: 576 tiles
        local = t - 1152; K = 3072; N = 768; ntn = 12;
        src = Wio + (size_t)l * 2359296;
        dst = WALL + (size_t)l * LW + W_IO_OFF;
    }
    int n0 = (local % ntn) * 64, k0 = (local / ntn) * 64;

    __shared__ float tl[64][65];
    int tx = tid & 15, ty = tid >> 4;    // tx: 4-float col group, ty: row
#pragma unroll
    for (int j = 0; j < 4; j++) {
        int k = ty + j * 16;
        float4 v = *(const float4*)(src + (size_t)(k0 + k) * N + n0 + tx * 4);
        tl[k][tx * 4 + 0] = v.x; tl[k][tx * 4 + 1] = v.y;
        tl[k][tx * 4 + 2] = v.z; tl[k][tx * 4 + 3] = v.w;
    }
    __syncthreads();
#pragma unroll
    for (int q = 0; q < 2; q++) {
        int chunk = q * 256 + tid;
        int row = chunk >> 3, c = chunk & 7;
        us8 o;
#pragma unroll
        for (int j = 0; j < 8; j++) o[j] = f2h(tl[c * 8 + j][row]);
        *(us8*)(dst + (size_t)(n0 + row) * K + k0 + c * 8) = o;
    }
}

// ---------------------------------------------------------------------------
// 192-thread LN reduction helper: thread i owns elems 4i..4i+3 of a 768-row.
// ---------------------------------------------------------------------------
__device__ __forceinline__ void ln_stats192(float4 v, float& mean, float& rstd) {
    float s = v.x + v.y + v.z + v.w;
    float s2 = v.x * v.x + v.y * v.y + v.z * v.z + v.w * v.w;
#pragma unroll
    for (int o = 32; o > 0; o >>= 1) { s += __shfl_xor(s, o); s2 += __shfl_xor(s2, o); }
    __shared__ float red[6];
    int lane = threadIdx.x & 63, wid = threadIdx.x >> 6;
    if (lane == 0) { red[wid] = s; red[3 + wid] = s2; }
    __syncthreads();
    float ts  = red[0] + red[1] + red[2];
    float ts2 = red[3] + red[4] + red[5];
    mean = ts * (1.0f / Hc);
    float var = ts2 * (1.0f / Hc) - mean * mean;
    rstd = rsqrtf(var + 1e-12f);
}

// ---------------------------------------------------------------------------
// Embedding + LayerNorm -> fp32 X and fp16 X  (192 threads, float4)
// ---------------------------------------------------------------------------
__global__ __launch_bounds__(192) void embed_ln_kernel(
    const int* __restrict__ ids, const int* __restrict__ seg,
    const float* __restrict__ tok, const float* __restrict__ typ,
    const float* __restrict__ pos, const float* __restrict__ g,
    const float* __restrict__ b, float* __restrict__ outf,
    unsigned short* __restrict__ outb)
{
    int t = blockIdx.x;
    int si = t % Sc;
    int id = ids[t], sg = seg[t];
    int i = threadIdx.x;

    float4 tv = *(const float4*)(tok + (size_t)id * Hc + 4 * i);
    float4 yv = *(const float4*)(typ + (size_t)sg * Hc + 4 * i);
    float4 pv = *(const float4*)(pos + (size_t)si * Hc + 4 * i);
    float4 v = make_float4(tv.x + yv.x + pv.x, tv.y + yv.y + pv.y,
                           tv.z + yv.z + pv.z, tv.w + yv.w + pv.w);
    float mean, rstd;
    ln_stats192(v, mean, rstd);

    float4 gv = *(const float4*)(g + 4 * i);
    float4 bv = *(const float4*)(b + 4 * i);
    float4 o = make_float4(gv.x * (v.x - mean) * rstd + bv.x,
                           gv.y * (v.y - mean) * rstd + bv.y,
                           gv.z * (v.z - mean) * rstd + bv.z,
                           gv.w * (v.w - mean) * rstd + bv.w);
    *(float4*)(outf + (size_t)t * Hc + 4 * i) = o;
    us4 ob; ob[0] = f2h(o.x); ob[1] = f2h(o.y); ob[2] = f2h(o.z); ob[3] = f2h(o.w);
    *(us4*)(outb + (size_t)t * Hc + 4 * i) = ob;
}

// ---------------------------------------------------------------------------
// (fp16 partial0 + fp16 partial1 + fp32 residual) -> LN -> fp32 + fp16
// ---------------------------------------------------------------------------
__global__ __launch_bounds__(192) void add_ln2h_kernel(
    const unsigned short* __restrict__ t0, const unsigned short* __restrict__ t1,
    const float* __restrict__ res, const float* __restrict__ g,
    const float* __restrict__ b, float* __restrict__ outf,
    unsigned short* __restrict__ outb)
{
    int t = blockIdx.x;
    int i = threadIdx.x;
    us4 a = *(const us4*)(t0 + (size_t)t * Hc + 4 * i);
    us4 c = *(const us4*)(t1 + (size_t)t * Hc + 4 * i);
    float4 r = *(const float4*)(res + (size_t)t * Hc + 4 * i);
    float4 v = make_float4(h2f(a[0]) + h2f(c[0]) + r.x,
                           h2f(a[1]) + h2f(c[1]) + r.y,
                           h2f(a[2]) + h2f(c[2]) + r.z,
                           h2f(a[3]) + h2f(c[3]) + r.w);
    float mean, rstd;
    ln_stats192(v, mean, rstd);

    float4 gv = *(const float4*)(g + 4 * i);
    float4 bv = *(const float4*)(b + 4 * i);
    float4 o = make_float4(gv.x * (v.x - mean) * rstd + bv.x,
                           gv.y * (v.y - mean) * rstd + bv.y,
                           gv.z * (v.z - mean) * rstd + bv.z,
                           gv.w * (v.w - mean) * rstd + bv.w);
    *(float4*)(outf + (size_t)t * Hc + 4 * i) = o;
    us4 ob; ob[0] = f2h(o.x); ob[1] = f2h(o.y); ob[2] = f2h(o.z); ob[3] = f2h(o.w);
    *(us4*)(outb + (size_t)t * Hc + 4 * i) = ob;
}

// ---------------------------------------------------------------------------
// FP16 MFMA GEMM (single-buffer m97 structure, ~4 blocks/CU) + XCD swizzle.
// OUT: 1 = gelu+fp16, 2 = fp16, 3 = QKV mode (col<1536 -> Cb ld 1536,
//      col>=1536 -> V transposed to VTp[B][NH][DH][S]),
//      4 = fp16 split-K partial to Cb + z*M*N (bias added on z==0 only)
// ---------------------------------------------------------------------------
template <int OUT>
__global__ __launch_bounds__(256) void gemm_mfma(
    const unsigned short* __restrict__ A,   // [M][K] fp16
    const unsigned short* __restrict__ Bt,  // [N][K] fp16
    const float* __restrict__ bias,         // [N]
    unsigned short* __restrict__ Cb,
    unsigned short* __restrict__ VTp,
    int M, int N, int K, int kspan)
{
    __shared__ __align__(16) unsigned short As[128 * 64];
    __shared__ __align__(16) unsigned short Bs[128 * 64];

    int tid = threadIdx.x;
    int l = tid & 63, w = tid >> 6;

    // XCD-aware swizzle (bijective: all grids here have nwg % 8 == 0)
    int nbx = gridDim.x;
    int nwg = nbx * gridDim.y;
    int bid = blockIdx.y * nbx + blockIdx.x;
    if ((nwg & 7) == 0) {
        int cpx = nwg >> 3;
        bid = (bid & 7) * cpx + (bid >> 3);
    }
    int m0 = (bid % nbx) * 128, n0 = (bid / nbx) * 128;

    int lr = l & 15;
    int kg = l >> 4;
    int wr = (w >> 1) * 64, wc = (w & 1) * 64;
    int lx = lr & 7;
    int kbeg = blockIdx.z * kspan;

    f32x4 acc[4][4] = {};

    for (int k0 = kbeg; k0 < kbeg + kspan; k0 += 64) {
#pragma unroll
        for (int p = 0; p < 4; p++) {
            int i = p * 256 + w * 64 + l;
            int row = i >> 3;
            int slot = (i & 7) ^ (row & 7);
            const unsigned short* ga = A + (size_t)(m0 + row) * K + k0 + slot * 8;
            const unsigned short* gb = Bt + (size_t)(n0 + row) * K + k0 + slot * 8;
            unsigned short* la = As + (size_t)(p * 256 + w * 64) * 8;
            unsigned short* lb = Bs + (size_t)(p * 256 + w * 64) * 8;
            gld_lds16(ga, la);
            gld_lds16(gb, lb);
        }
        asm volatile("s_waitcnt vmcnt(0)" ::: "memory");
        __syncthreads();

#pragma unroll
        for (int kh = 0; kh < 2; kh++) {
            h16x8 av[4], bv[4];
#pragma unroll
            for (int f = 0; f < 4; f++) {
                int sl = (kh * 4 + kg) ^ lx;
                av[f] = *(const h16x8*)(As + (wr + f * 16 + lr) * 64 + sl * 8);
                bv[f] = *(const h16x8*)(Bs + (wc + f * 16 + lr) * 64 + sl * 8);
            }
#pragma unroll
            for (int i = 0; i < 4; i++)
#pragma unroll
                for (int j = 0; j < 4; j++)
                    acc[i][j] = __builtin_amdgcn_mfma_f32_16x16x32_f16(
                        av[i], bv[j], acc[i][j], 0, 0, 0);
        }
        __syncthreads();
    }

#pragma unroll
    for (int i = 0; i < 4; i++) {
        int rbase = m0 + wr + i * 16 + kg * 4;
#pragma unroll
        for (int j = 0; j < 4; j++) {
            int col = n0 + wc + j * 16 + lr;
            float bcol = (OUT == 4 && blockIdx.z > 0) ? 0.f : bias[col];
            if (OUT == 3 && col >= 1536) {
                // V columns -> transposed store VT[b][h][d][s]
                int vcol = col - 1536;
                int hh = vcol >> 6, d = vcol & 63;
                int bbb = rbase >> 9, s0 = rbase & 511;
                us4 ob;
#pragma unroll
                for (int r = 0; r < 4; r++) ob[r] = f2h(acc[i][j][r] + bcol);
                *(us4*)(VTp + ((((size_t)bbb * NHc + hh) * DHc + d) << 9) + s0) = ob;
            } else if (OUT == 4) {
                unsigned short* op = Cb + (size_t)blockIdx.z * M * N;
#pragma unroll
                for (int r = 0; r < 4; r++)
                    op[(size_t)(rbase + r) * N + col] = f2h(acc[i][j][r] + bcol);
            } else {
                int ldc = (OUT == 3) ? 1536 : N;
#pragma unroll
                for (int r = 0; r < 4; r++) {
                    float v = acc[i][j][r] + bcol;
                    if (OUT == 1) v = 0.5f * v * (1.0f + erff(v * 0.70710678118654752f));
                    Cb[(size_t)(rbase + r) * ldc + col] = f2h(v);
                }
            }
        }
    }
}

// ---------------------------------------------------------------------------
// MFMA flash attention (exact round-9/10 KVBLK=64 version: 16.5 KB LDS,
// 8 blocks/CU, unconditional online-softmax rescale).
// QK fp16 [NTOK][1536] (Q at 0, K at 768); VT fp16 [B][NH][DH][S].
// Out ctx fp16 [NTOK][768].
// S^T = mfma(K, Q) -> lane owns q-col c = l&15, kv rows 16f+4g+r.
// O^T = mfma(Vt, P^T) -> lane owns O[q=c][d=16fm+4g+r].
// ---------------------------------------------------------------------------
__global__ __launch_bounds__(256) void attn_mfma(
    const unsigned short* __restrict__ QK, const unsigned short* __restrict__ VT,
    const float* __restrict__ mask, unsigned short* __restrict__ O)
{
    const int LD = 1536;
    __shared__ __align__(16) unsigned short Ks[64 * 64];
    __shared__ __align__(16) unsigned short Vt[64 * 64];   // [d][kv], swizzled
    __shared__ float Ml[64];

    int tid = threadIdx.x;
    int l = tid & 63, w = tid >> 6;
    int g = l >> 4, c = l & 15;
    int q0 = blockIdx.x * 64;
    int h = blockIdx.y, bb = blockIdx.z;

    // Q fragment (B-operand of S^T mfma): Q[q=c][d = 32*kh + 8g + j]
    const size_t rowQ = (size_t)(bb * Sc + q0 + w * 16 + c) * LD + h * DHc;
    h16x8 qv[2];
    qv[0] = *(const h16x8*)(QK + rowQ + 8 * g);
    qv[1] = *(const h16x8*)(QK + rowQ + 32 + 8 * g);

    float m_run = -1e30f, l_run = 0.f;
    f32x4 acc_o[4] = {};
    const float scale = 0.125f;

    for (int kt = 0; kt < Sc; kt += 64) {
        // ---- stage K tile (swizzled source -> linear LDS) ----
        const unsigned short* Kgb = QK + (size_t)(bb * Sc + kt) * LD + Hc + h * DHc;
#pragma unroll
        for (int p = 0; p < 2; p++) {
            int i = p * 256 + tid;
            int row = i >> 3;
            int slot = (i & 7) ^ (row & 7);
            gld_lds16(Kgb + (size_t)row * LD + slot * 8, Ks + (size_t)(p * 256 + w * 64) * 8);
        }
        // ---- stage V^T tile from VT[b][h][d][s] (row d, 64 s each) ----
        const unsigned short* Vg = VT + (((size_t)bb * NHc + h) * DHc << 9) + kt;
#pragma unroll
        for (int p = 0; p < 2; p++) {
            int i = p * 256 + tid;
            int row = i >> 3;
            int slot = (i & 7) ^ (row & 7);
            gld_lds16(Vg + ((size_t)row << 9) + slot * 8, Vt + (size_t)(p * 256 + w * 64) * 8);
        }
        if (tid < 64) Ml[tid] = (1.0f - mask[bb * Sc + kt + tid]) * -10000.0f;
        asm volatile("s_waitcnt vmcnt(0)" ::: "memory");
        __syncthreads();

        // ---- S^T = K @ Q^T : rows kv (4 frags), cols q ----
        f32x4 s[4] = {};
#pragma unroll
        for (int kh = 0; kh < 2; kh++) {
#pragma unroll
            for (int f = 0; f < 4; f++) {
                int row = f * 16 + c;
                h16x8 av = *(const h16x8*)(Ks + row * 64 + (((kh * 4 + g) ^ (row & 7)) * 8));
                s[f] = __builtin_amdgcn_mfma_f32_16x16x32_f16(av, qv[kh], s[f], 0, 0, 0);
            }
        }

        // ---- softmax (per q = c, values spread over g-groups) ----
        f32x4 mv[4];
#pragma unroll
        for (int f = 0; f < 4; f++) mv[f] = *(const f32x4*)&Ml[f * 16 + 4 * g];
        float mx = -1e30f;
#pragma unroll
        for (int f = 0; f < 4; f++)
#pragma unroll
            for (int r = 0; r < 4; r++) {
                float sv = s[f][r] * scale + mv[f][r];
                s[f][r] = sv;
                mx = fmaxf(mx, sv);
            }
        mx = fmaxf(mx, __shfl_xor(mx, 16));
        mx = fmaxf(mx, __shfl_xor(mx, 32));
        float mn = fmaxf(m_run, mx);
        float fs = __expf(m_run - mn);
        m_run = mn;
        float ps = 0.f;
        f32x4 p[4];
#pragma unroll
        for (int f = 0; f < 4; f++)
#pragma unroll
            for (int r = 0; r < 4; r++) {
                float pv = __expf(s[f][r] - mn);
                p[f][r] = pv;
                ps += pv;
            }
        ps += __shfl_xor(ps, 16);
        ps += __shfl_xor(ps, 32);
        l_run = l_run * fs + ps;
#pragma unroll
        for (int fm = 0; fm < 4; fm++)
#pragma unroll
            for (int r = 0; r < 4; r++) acc_o[fm][r] *= fs;

        // ---- pack P to fp16 pairs ----
        unsigned pk[4][2];
#pragma unroll
        for (int f = 0; f < 4; f++)
#pragma unroll
            for (int rp = 0; rp < 2; rp++)
                pk[f][rp] = ((unsigned)f2h(p[f][2 * rp + 1]) << 16) | f2h(p[f][2 * rp]);

        // ---- PV: O^T += Vt @ P^T ----
        // dest lane (g,c) word t needs P[q=c][kv=32kh+8g+2t+{0,1}] =
        // pk[2kh + (g>>1)][t&1] from lane g_src = 2(g&1)+(t>>1);
        // f-select AFTER shuffle (uses dest g).
#pragma unroll
        for (int kh = 0; kh < 2; kh++) {
            u32x4 bw;
#pragma unroll
            for (int t = 0; t < 4; t++) {
                int srcl = (2 * ((l >> 4) & 1) + (t >> 1)) * 16 + c;
                unsigned lo = __shfl(pk[2 * kh][t & 1], srcl);
                unsigned hi = __shfl(pk[2 * kh + 1][t & 1], srcl);
                bw[t] = (g & 2) ? hi : lo;
            }
            h16x8 bfrag = __builtin_bit_cast(h16x8, bw);
#pragma unroll
            for (int fm = 0; fm < 4; fm++) {
                int row = fm * 16 + c;
                h16x8 av = *(const h16x8*)(Vt + row * 64 + (((kh * 4 + g) ^ (row & 7)) * 8));
                acc_o[fm] = __builtin_amdgcn_mfma_f32_16x16x32_f16(av, bfrag, acc_o[fm], 0, 0, 0);
            }
        }
        __syncthreads();
    }

    // ---- epilogue: O[q=c][d = 16fm + 4g + r] / l ----
    float rl = 1.0f / l_run;
    size_t tokrow = (size_t)(bb * Sc + q0 + w * 16 + c) * Hc + h * DHc;
#pragma unroll
    for (int fm = 0; fm < 4; fm++) {
        us4 ob;
#pragma unroll
        for (int r = 0; r < 4; r++) ob[r] = f2h(acc_o[fm][r] * rl);
        *(us4*)(O + tokrow + fm * 16 + 4 * g) = ob;
    }
}

// ---------------------------------------------------------------------------
extern "C" void kernel_launch(void* const* d_in, const int* in_sizes, int n_in,
                              void* d_out, int out_size, void* d_ws, size_t ws_size,
                              hipStream_t stream)
{
    const int*   input_ids      = (const int*)  d_in[0];
    const int*   segment_ids    = (const int*)  d_in[1];
    const float* attention_mask = (const float*)d_in[2];
    const float* tok_emb = (const float*)d_in[3];
    const float* pos_emb = (const float*)d_in[4];
    const float* type_emb= (const float*)d_in[5];
    const float* emb_g   = (const float*)d_in[6];
    const float* emb_b   = (const float*)d_in[7];
    const float* Wq  = (const float*)d_in[8];  const float* bq  = (const float*)d_in[9];
    const float* Wk  = (const float*)d_in[10]; const float* bk  = (const float*)d_in[11];
    const float* Wv  = (const float*)d_in[12]; const float* bv  = (const float*)d_in[13];
    const float* Wao = (const float*)d_in[14]; const float* bao = (const float*)d_in[15];
    const float* ln1_g = (const float*)d_in[16]; const float* ln1_b = (const float*)d_in[17];
    const float* Wi  = (const float*)d_in[18]; const float* bi  = (const float*)d_in[19];
    const float* Wio = (const float*)d_in[20]; const float* bio = (const float*)d_in[21];
    const float* ln2_g = (const float*)d_in[22]; const float* ln2_b = (const float*)d_in[23];

    float* out = (float*)d_out;

    const size_t NT = (size_t)NTOK * Hc;
    float* Xf   = (float*)d_ws;
    float* XAf  = Xf + NT;
    float* BALL = XAf + NT;                                  // 12*2304 fp32
    unsigned short* QKb = (unsigned short*)(BALL + (size_t)Lc * QKVN);
    unsigned short* VT  = QKb + (size_t)NTOK * 1536;         // [B][NH][DH][S]
    unsigned short* Xb  = VT + NT;
    unsigned short* XAb = Xb + NT;
    unsigned short* Cb  = XAb + NT;
    unsigned short* Tp  = Cb + NT;                           // 2 x NT fp16 split-K partials
    unsigned short* Hb  = Tp + 2 * NT;                       // [NTOK][3072]
    unsigned short* WALL = Hb + (size_t)NTOK * Fc;           // 12 * LW fp16

    // ---- one-shot prep: all weight transposes + bias concat ----
    prep_kernel<<<dim3(1737, Lc), 256, 0, stream>>>(Wq, Wk, Wv, Wao, Wi, Wio,
                                                    bq, bk, bv, WALL, BALL);

    embed_ln_kernel<<<NTOK, 192, 0, stream>>>(input_ids, segment_ids, tok_emb,
                                              type_emb, pos_emb, emb_g, emb_b, Xf, Xb);

    dim3 gQKV(NTOK / 128, QKVN / 128);      // 32 x 18
    dim3 gF(NTOK / 128, Fc / 128);          // 32 x 24
    dim3 gH2(NTOK / 128, Hc / 128, 2);      // 32 x 6 x 2 (split-K AO/FFN2)
    dim3 gA(Sc / 64, NHc, Bc);              // 8 x 12 x 8

    for (int l = 0; l < Lc; l++) {
        const unsigned short* WqkvT = WALL + (size_t)l * LW + W_QKV_OFF;
        const unsigned short* WaoT  = WALL + (size_t)l * LW + W_AO_OFF;
        const unsigned short* WiT   = WALL + (size_t)l * LW + W_I_OFF;
        const unsigned short* WioT  = WALL + (size_t)l * LW + W_IO_OFF;
        const float* bqkv = BALL + (size_t)l * QKVN;

        // fused QKV GEMM -> QKb (Q,K) + VT (V transposed)
        gemm_mfma<3><<<gQKV, 256, 0, stream>>>(Xb, WqkvT, bqkv, QKb, VT,
                                               NTOK, QKVN, Hc, Hc);
        attn_mfma<<<gA, 256, 0, stream>>>(QKb, VT, attention_mask, Cb);

        // attention-out dense, split-K=2 -> fp16 partials
        gemm_mfma<4><<<gH2, 256, 0, stream>>>(Cb, WaoT, bao + (size_t)l * Hc, Tp,
                                              nullptr, NTOK, Hc, Hc, Hc / 2);
        add_ln2h_kernel<<<NTOK, 192, 0, stream>>>(Tp, Tp + NT, Xf,
                                                  ln1_g + (size_t)l * Hc,
                                                  ln1_b + (size_t)l * Hc, XAf, XAb);

        // FFN1 + gelu -> Hb (fp16)
        gemm_mfma<1><<<gF, 256, 0, stream>>>(XAb, WiT, bi + (size_t)l * Fc, Hb,
                                             nullptr, NTOK, Fc, Hc, Hc);
        // FFN2 split-K=2 -> fp16 partials
        gemm_mfma<4><<<gH2, 256, 0, stream>>>(Hb, WioT, bio + (size_t)l * Hc, Tp,
                                              nullptr, NTOK, Hc, Fc, Fc / 2);
        float* xout = (l == Lc - 1) ? out : Xf;
        add_ln2h_kernel<<<NTOK, 192, 0, stream>>>(Tp, Tp + NT, XAf,
                                                  ln2_g + (size_t)l * Hc,
                                                  ln2_b + (size_t)l * Hc, xout, Xb);
    }
}

// Round 14
// 1953.356 us; speedup vs baseline: 1.1309x; 1.0402x over previous
//
#include <hip/hip_runtime.h>
#include <math.h>

// Problem constants
static constexpr int Bc = 8;
static constexpr int Sc = 512;
static constexpr int Hc = 768;
static constexpr int NHc = 12;
static constexpr int Lc = 12;
static constexpr int Fc = 3072;
static constexpr int DHc = 64;
static constexpr int NTOK = Bc * Sc;      // 4096
static constexpr int QKVN = 3 * Hc;       // 2304

// all-layer transposed-weight block offsets (fp16 elements).
// Weights are stored TILED: [N/128][K/64][128][64] (tile = 8192 elems),
// matching exactly what one GEMM block stages per K-step.
static constexpr size_t W_QKV_OFF = 0;                    // 216 tiles
static constexpr size_t W_AO_OFF  = 1769472;              // 72 tiles
static constexpr size_t W_I_OFF   = 2359296;              // 288 tiles
static constexpr size_t W_IO_OFF  = 4718592;              // 288 tiles
static constexpr size_t LW        = 7077888;              // per-layer total

typedef _Float16 h16x8 __attribute__((ext_vector_type(8)));
typedef float f32x4 __attribute__((ext_vector_type(4)));
typedef unsigned short us4 __attribute__((ext_vector_type(4)));
typedef unsigned short us8 __attribute__((ext_vector_type(8)));
typedef unsigned int u32x4 __attribute__((ext_vector_type(4)));

__device__ __forceinline__ unsigned short f2h(float f) {
    _Float16 h = (_Float16)f;                    // v_cvt_f16_f32, RTE
    return __builtin_bit_cast(unsigned short, h);
}
__device__ __forceinline__ float h2f(unsigned short u) {
    return (float)__builtin_bit_cast(_Float16, u);
}

#define AS1 __attribute__((address_space(1)))
#define AS3 __attribute__((address_space(3)))
__device__ __forceinline__ void gld_lds16(const void* g, void* l) {
    __builtin_amdgcn_global_load_lds((const AS1 void*)g, (AS3 void*)l, 16, 0, 0);
}

// ---------------------------------------------------------------------------
// ALL-layer weight prep: same 64x64 transpose tiles (best-measured read+LDS
// structure), but dst is the TILED layout -> each block's writes are a
// perfectly sequential 8 KB stream (chunk*16B), fixing the 2.5 TB/s
// scattered-write bottleneck.
// blockIdx.y = layer; blockIdx.x: 1728 tiles + 9 bias blocks.
// ---------------------------------------------------------------------------
__global__ __launch_bounds__(256) void prep_kernel(
    const float* __restrict__ Wq, const float* __restrict__ Wk,
    const float* __restrict__ Wv, const float* __restrict__ Wao,
    const float* __restrict__ Wi, const float* __restrict__ Wio,
    const float* __restrict__ bq, const float* __restrict__ bk,
    const float* __restrict__ bv, unsigned short* __restrict__ WALL,
    float* __restrict__ BALL)
{
    int t = blockIdx.x, l = blockIdx.y;
    int tid = threadIdx.x;

    if (t >= 1728) {   // bias concat: 9 blocks x 256 = 2304
        int idx = (t - 1728) * 256 + tid;
        float v = (idx < 768) ? bq[l * Hc + idx]
                : (idx < 1536) ? bk[l * Hc + idx - 768]
                               : bv[l * Hc + idx - 1536];
        BALL[(size_t)l * QKVN + idx] = v;
        return;
    }

    const float* src;
    unsigned short* dst;
    int K, N, ntn, local;
    if (t < 576) {                       // Wq,Wk,Wv,Wao: 144 tiles each
        int mat = t / 144; local = t % 144;
        K = 768; N = 768; ntn = 12;
        src = (mat == 0 ? Wq : mat == 1 ? Wk : mat == 2 ? Wv : Wao) + (size_t)l * 589824;
        dst = WALL + (size_t)l * LW + (mat < 3 ? (size_t)mat * 589824 : W_AO_OFF);
    } else if (t < 1152) {               // Wi: 576 tiles
        local = t - 576; K = 768; N = 3072; ntn = 48;
        src = Wi + (size_t)l * 2359296;
        dst = WALL + (size_t)l * LW + W_I_OFF;
    } else {                             // Wio: 576 tiles
        local = t - 1152; K = 3072; N = 768; ntn = 12;
        src = Wio + (size_t)l * 2359296;
        dst = WALL + (size_t)l * LW + W_IO_OFF;
    }
    int n0 = (local % ntn) * 64, k0 = (local / ntn) * 64;

    // tiled dst: tile (n0>>7, k0>>6), half-tile select on bit 6 of n0
    int nkt = K >> 6;
    unsigned short* dstb = dst + ((size_t)(n0 >> 7) * nkt + (k0 >> 6)) * 8192
                               + ((n0 >> 6) & 1) * 4096;

    __shared__ float tl[64][65];
    int tx = tid & 15, ty = tid >> 4;    // tx: 4-float col group, ty: row
#pragma unroll
    for (int j = 0; j < 4; j++) {
        int k = ty + j * 16;
        float4 v = *(const float4*)(src + (size_t)(k0 + k) * N + n0 + tx * 4);
        tl[k][tx * 4 + 0] = v.x; tl[k][tx * 4 + 1] = v.y;
        tl[k][tx * 4 + 2] = v.z; tl[k][tx * 4 + 3] = v.w;
    }
    __syncthreads();
#pragma unroll
    for (int q = 0; q < 2; q++) {
        int chunk = q * 256 + tid;
        int row = chunk >> 3, c = chunk & 7;
        us8 o;
#pragma unroll
        for (int j = 0; j < 8; j++) o[j] = f2h(tl[c * 8 + j][row]);
        *(us8*)(dstb + (size_t)chunk * 8) = o;   // sequential stream
    }
}

// ---------------------------------------------------------------------------
// 192-thread LN reduction helper: thread i owns elems 4i..4i+3 of a 768-row.
// ---------------------------------------------------------------------------
__device__ __forceinline__ void ln_stats192(float4 v, float& mean, float& rstd) {
    float s = v.x + v.y + v.z + v.w;
    float s2 = v.x * v.x + v.y * v.y + v.z * v.z + v.w * v.w;
#pragma unroll
    for (int o = 32; o > 0; o >>= 1) { s += __shfl_xor(s, o); s2 += __shfl_xor(s2, o); }
    __shared__ float red[6];
    int lane = threadIdx.x & 63, wid = threadIdx.x >> 6;
    if (lane == 0) { red[wid] = s; red[3 + wid] = s2; }
    __syncthreads();
    float ts  = red[0] + red[1] + red[2];
    float ts2 = red[3] + red[4] + red[5];
    mean = ts * (1.0f / Hc);
    float var = ts2 * (1.0f / Hc) - mean * mean;
    rstd = rsqrtf(var + 1e-12f);
}

// ---------------------------------------------------------------------------
// Embedding + LayerNorm -> fp16 X  (192 threads, float4)
// ---------------------------------------------------------------------------
__global__ __launch_bounds__(192) void embed_ln_kernel(
    const int* __restrict__ ids, const int* __restrict__ seg,
    const float* __restrict__ tok, const float* __restrict__ typ,
    const float* __restrict__ pos, const float* __restrict__ g,
    const float* __restrict__ b, unsigned short* __restrict__ outb)
{
    int t = blockIdx.x;
    int si = t % Sc;
    int id = ids[t], sg = seg[t];
    int i = threadIdx.x;

    float4 tv = *(const float4*)(tok + (size_t)id * Hc + 4 * i);
    float4 yv = *(const float4*)(typ + (size_t)sg * Hc + 4 * i);
    float4 pv = *(const float4*)(pos + (size_t)si * Hc + 4 * i);
    float4 v = make_float4(tv.x + yv.x + pv.x, tv.y + yv.y + pv.y,
                           tv.z + yv.z + pv.z, tv.w + yv.w + pv.w);
    float mean, rstd;
    ln_stats192(v, mean, rstd);

    float4 gv = *(const float4*)(g + 4 * i);
    float4 bv = *(const float4*)(b + 4 * i);
    us4 ob;
    ob[0] = f2h(gv.x * (v.x - mean) * rstd + bv.x);
    ob[1] = f2h(gv.y * (v.y - mean) * rstd + bv.y);
    ob[2] = f2h(gv.z * (v.z - mean) * rstd + bv.z);
    ob[3] = f2h(gv.w * (v.w - mean) * rstd + bv.w);
    *(us4*)(outb + (size_t)t * Hc + 4 * i) = ob;
}

// ---------------------------------------------------------------------------
// (fp16 partial0 + fp16 partial1 + fp16 residual) -> LN -> fp16
// (+ fp32 out on final layer via nullable outf)
// ---------------------------------------------------------------------------
__global__ __launch_bounds__(192) void add_ln2h_kernel(
    const unsigned short* __restrict__ t0, const unsigned short* __restrict__ t1,
    const unsigned short* __restrict__ res, const float* __restrict__ g,
    const float* __restrict__ b, unsigned short* __restrict__ outb,
    float* __restrict__ outf)
{
    int t = blockIdx.x;
    int i = threadIdx.x;
    us4 a = *(const us4*)(t0 + (size_t)t * Hc + 4 * i);
    us4 c = *(const us4*)(t1 + (size_t)t * Hc + 4 * i);
    us4 r = *(const us4*)(res + (size_t)t * Hc + 4 * i);
    float4 v = make_float4(h2f(a[0]) + h2f(c[0]) + h2f(r[0]),
                           h2f(a[1]) + h2f(c[1]) + h2f(r[1]),
                           h2f(a[2]) + h2f(c[2]) + h2f(r[2]),
                           h2f(a[3]) + h2f(c[3]) + h2f(r[3]));
    float mean, rstd;
    ln_stats192(v, mean, rstd);

    float4 gv = *(const float4*)(g + 4 * i);
    float4 bv = *(const float4*)(b + 4 * i);
    float4 o = make_float4(gv.x * (v.x - mean) * rstd + bv.x,
                           gv.y * (v.y - mean) * rstd + bv.y,
                           gv.z * (v.z - mean) * rstd + bv.z,
                           gv.w * (v.w - mean) * rstd + bv.w);
    us4 ob; ob[0] = f2h(o.x); ob[1] = f2h(o.y); ob[2] = f2h(o.z); ob[3] = f2h(o.w);
    *(us4*)(outb + (size_t)t * Hc + 4 * i) = ob;
    if (outf) *(float4*)(outf + (size_t)t * Hc + 4 * i) = o;
}

// ---------------------------------------------------------------------------
// FP16 MFMA GEMM (single-buffer m97 structure, ~4 blocks/CU) + XCD swizzle.
// B is in TILED layout [N/128][K/64][128][64] -> B staging reads are a
// contiguous 16 KB block per K-step.
// OUT: 1 = gelu+fp16, 2 = fp16, 3 = QKV mode (col<1536 -> Cb ld 1536,
//      col>=1536 -> V transposed to VTp[B][NH][DH][S]),
//      4 = fp16 split-K partial to Cb + z*M*N (bias added on z==0 only)
// ---------------------------------------------------------------------------
template <int OUT>
__global__ __launch_bounds__(256) void gemm_mfma(
    const unsigned short* __restrict__ A,   // [M][K] fp16
    const unsigned short* __restrict__ Bt,  // tiled fp16
    const float* __restrict__ bias,         // [N]
    unsigned short* __restrict__ Cb,
    unsigned short* __restrict__ VTp,
    int M, int N, int K, int kspan)
{
    __shared__ __align__(16) unsigned short As[128 * 64];
    __shared__ __align__(16) unsigned short Bs[128 * 64];

    int tid = threadIdx.x;
    int l = tid & 63, w = tid >> 6;

    // XCD-aware swizzle (bijective: all grids here have nwg % 8 == 0)
    int nbx = gridDim.x;
    int nwg = nbx * gridDim.y;
    int bid = blockIdx.y * nbx + blockIdx.x;
    if ((nwg & 7) == 0) {
        int cpx = nwg >> 3;
        bid = (bid & 7) * cpx + (bid >> 3);
    }
    int m0 = (bid % nbx) * 128, n0 = (bid / nbx) * 128;

    int lr = l & 15;
    int kg = l >> 4;
    int wr = (w >> 1) * 64, wc = (w & 1) * 64;
    int lx = lr & 7;
    int kbeg = blockIdx.z * kspan;
    int nkt = K >> 6;
    const unsigned short* BtRow = Bt + (size_t)(n0 >> 7) * nkt * 8192;

    f32x4 acc[4][4] = {};

    for (int k0 = kbeg; k0 < kbeg + kspan; k0 += 64) {
        const unsigned short* gbBase = BtRow + (size_t)(k0 >> 6) * 8192;
#pragma unroll
        for (int p = 0; p < 4; p++) {
            int i = p * 256 + w * 64 + l;
            int row = i >> 3;
            int slot = (i & 7) ^ (row & 7);
            const unsigned short* ga = A + (size_t)(m0 + row) * K + k0 + slot * 8;
            const unsigned short* gb = gbBase + row * 64 + slot * 8;
            unsigned short* la = As + (size_t)(p * 256 + w * 64) * 8;
            unsigned short* lb = Bs + (size_t)(p * 256 + w * 64) * 8;
            gld_lds16(ga, la);
            gld_lds16(gb, lb);
        }
        asm volatile("s_waitcnt vmcnt(0)" ::: "memory");
        __syncthreads();

#pragma unroll
        for (int kh = 0; kh < 2; kh++) {
            h16x8 av[4], bv[4];
#pragma unroll
            for (int f = 0; f < 4; f++) {
                int sl = (kh * 4 + kg) ^ lx;
                av[f] = *(const h16x8*)(As + (wr + f * 16 + lr) * 64 + sl * 8);
                bv[f] = *(const h16x8*)(Bs + (wc + f * 16 + lr) * 64 + sl * 8);
            }
#pragma unroll
            for (int i = 0; i < 4; i++)
#pragma unroll
                for (int j = 0; j < 4; j++)
                    acc[i][j] = __builtin_amdgcn_mfma_f32_16x16x32_f16(
                        av[i], bv[j], acc[i][j], 0, 0, 0);
        }
        __syncthreads();
    }

#pragma unroll
    for (int i = 0; i < 4; i++) {
        int rbase = m0 + wr + i * 16 + kg * 4;
#pragma unroll
        for (int j = 0; j < 4; j++) {
            int col = n0 + wc + j * 16 + lr;
            float bcol = (OUT == 4 && blockIdx.z > 0) ? 0.f : bias[col];
            if (OUT == 3 && col >= 1536) {
                // V columns -> transposed store VT[b][h][d][s]
                int vcol = col - 1536;
                int hh = vcol >> 6, d = vcol & 63;
                int bbb = rbase >> 9, s0 = rbase & 511;
                us4 ob;
#pragma unroll
                for (int r = 0; r < 4; r++) ob[r] = f2h(acc[i][j][r] + bcol);
                *(us4*)(VTp + ((((size_t)bbb * NHc + hh) * DHc + d) << 9) + s0) = ob;
            } else if (OUT == 4) {
                unsigned short* op = Cb + (size_t)blockIdx.z * M * N;
#pragma unroll
                for (int r = 0; r < 4; r++)
                    op[(size_t)(rbase + r) * N + col] = f2h(acc[i][j][r] + bcol);
            } else {
                int ldc = (OUT == 3) ? 1536 : N;
#pragma unroll
                for (int r = 0; r < 4; r++) {
                    float v = acc[i][j][r] + bcol;
                    if (OUT == 1) v = 0.5f * v * (1.0f + erff(v * 0.70710678118654752f));
                    Cb[(size_t)(rbase + r) * ldc + col] = f2h(v);
                }
            }
        }
    }
}

// ---------------------------------------------------------------------------
// MFMA flash attention (KVBLK=64, 16.5 KB LDS, 8 blocks/CU, unconditional
// online-softmax rescale — the verified round-9/10 structure).
// QK fp16 [NTOK][1536] (Q at 0, K at 768); VT fp16 [B][NH][DH][S].
// Out ctx fp16 [NTOK][768].
// ---------------------------------------------------------------------------
__global__ __launch_bounds__(256) void attn_mfma(
    const unsigned short* __restrict__ QK, const unsigned short* __restrict__ VT,
    const float* __restrict__ mask, unsigned short* __restrict__ O)
{
    const int LD = 1536;
    __shared__ __align__(16) unsigned short Ks[64 * 64];
    __shared__ __align__(16) unsigned short Vt[64 * 64];   // [d][kv], swizzled
    __shared__ float Ml[64];

    int tid = threadIdx.x;
    int l = tid & 63, w = tid >> 6;
    int g = l >> 4, c = l & 15;
    int q0 = blockIdx.x * 64;
    int h = blockIdx.y, bb = blockIdx.z;

    // Q fragment (B-operand of S^T mfma): Q[q=c][d = 32*kh + 8g + j]
    const size_t rowQ = (size_t)(bb * Sc + q0 + w * 16 + c) * LD + h * DHc;
    h16x8 qv[2];
    qv[0] = *(const h16x8*)(QK + rowQ + 8 * g);
    qv[1] = *(const h16x8*)(QK + rowQ + 32 + 8 * g);

    float m_run = -1e30f, l_run = 0.f;
    f32x4 acc_o[4] = {};
    const float scale = 0.125f;

    for (int kt = 0; kt < Sc; kt += 64) {
        // ---- stage K tile (swizzled source -> linear LDS) ----
        const unsigned short* Kgb = QK + (size_t)(bb * Sc + kt) * LD + Hc + h * DHc;
#pragma unroll
        for (int p = 0; p < 2; p++) {
            int i = p * 256 + tid;
            int row = i >> 3;
            int slot = (i & 7) ^ (row & 7);
            gld_lds16(Kgb + (size_t)row * LD + slot * 8, Ks + (size_t)(p * 256 + w * 64) * 8);
        }
        // ---- stage V^T tile from VT[b][h][d][s] (row d, 64 s each) ----
        const unsigned short* Vg = VT + (((size_t)bb * NHc + h) * DHc << 9) + kt;
#pragma unroll
        for (int p = 0; p < 2; p++) {
            int i = p * 256 + tid;
            int row = i >> 3;
            int slot = (i & 7) ^ (row & 7);
            gld_lds16(Vg + ((size_t)row << 9) + slot * 8, Vt + (size_t)(p * 256 + w * 64) * 8);
        }
        if (tid < 64) Ml[tid] = (1.0f - mask[bb * Sc + kt + tid]) * -10000.0f;
        asm volatile("s_waitcnt vmcnt(0)" ::: "memory");
        __syncthreads();

        // ---- S^T = K @ Q^T : rows kv (4 frags), cols q ----
        f32x4 s[4] = {};
#pragma unroll
        for (int kh = 0; kh < 2; kh++) {
#pragma unroll
            for (int f = 0; f < 4; f++) {
                int row = f * 16 + c;
                h16x8 av = *(const h16x8*)(Ks + row * 64 + (((kh * 4 + g) ^ (row & 7)) * 8));
                s[f] = __builtin_amdgcn_mfma_f32_16x16x32_f16(av, qv[kh], s[f], 0, 0, 0);
            }
        }

        // ---- softmax (per q = c, values spread over g-groups) ----
        f32x4 mv[4];
#pragma unroll
        for (int f = 0; f < 4; f++) mv[f] = *(const f32x4*)&Ml[f * 16 + 4 * g];
        float mx = -1e30f;
#pragma unroll
        for (int f = 0; f < 4; f++)
#pragma unroll
            for (int r = 0; r < 4; r++) {
                float sv = s[f][r] * scale + mv[f][r];
                s[f][r] = sv;
                mx = fmaxf(mx, sv);
            }
        mx = fmaxf(mx, __shfl_xor(mx, 16));
        mx = fmaxf(mx, __shfl_xor(mx, 32));
        float mn = fmaxf(m_run, mx);
        float fs = __expf(m_run - mn);
        m_run = mn;
        float ps = 0.f;
        f32x4 p[4];
#pragma unroll
        for (int f = 0; f < 4; f++)
#pragma unroll
            for (int r = 0; r < 4; r++) {
                float pv = __expf(s[f][r] - mn);
                p[f][r] = pv;
                ps += pv;
            }
        ps += __shfl_xor(ps, 16);
        ps += __shfl_xor(ps, 32);
        l_run = l_run * fs + ps;
#pragma unroll
        for (int fm = 0; fm < 4; fm++)
#pragma unroll
            for (int r = 0; r < 4; r++) acc_o[fm][r] *= fs;

        // ---- pack P to fp16 pairs ----
        unsigned pk[4][2];
#pragma unroll
        for (int f = 0; f < 4; f++)
#pragma unroll
            for (int rp = 0; rp < 2; rp++)
                pk[f][rp] = ((unsigned)f2h(p[f][2 * rp + 1]) << 16) | f2h(p[f][2 * rp]);

        // ---- PV: O^T += Vt @ P^T ----
        // dest lane (g,c) word t needs P[q=c][kv=32kh+8g+2t+{0,1}] =
        // pk[2kh + (g>>1)][t&1] from lane g_src = 2(g&1)+(t>>1);
        // f-select AFTER shuffle (uses dest g).
#pragma unroll
        for (int kh = 0; kh < 2; kh++) {
            u32x4 bw;
#pragma unroll
            for (int t = 0; t < 4; t++) {
                int srcl = (2 * ((l >> 4) & 1) + (t >> 1)) * 16 + c;
                unsigned lo = __shfl(pk[2 * kh][t & 1], srcl);
                unsigned hi = __shfl(pk[2 * kh + 1][t & 1], srcl);
                bw[t] = (g & 2) ? hi : lo;
            }
            h16x8 bfrag = __builtin_bit_cast(h16x8, bw);
#pragma unroll
            for (int fm = 0; fm < 4; fm++) {
                int row = fm * 16 + c;
                h16x8 av = *(const h16x8*)(Vt + row * 64 + (((kh * 4 + g) ^ (row & 7)) * 8));
                acc_o[fm] = __builtin_amdgcn_mfma_f32_16x16x32_f16(av, bfrag, acc_o[fm], 0, 0, 0);
            }
        }
        __syncthreads();
    }

    // ---- epilogue: O[q=c][d = 16fm + 4g + r] / l ----
    float rl = 1.0f / l_run;
    size_t tokrow = (size_t)(bb * Sc + q0 + w * 16 + c) * Hc + h * DHc;
#pragma unroll
    for (int fm = 0; fm < 4; fm++) {
        us4 ob;
#pragma unroll
        for (int r = 0; r < 4; r++) ob[r] = f2h(acc_o[fm][r] * rl);
        *(us4*)(O + tokrow + fm * 16 + 4 * g) = ob;
    }
}

// ---------------------------------------------------------------------------
extern "C" void kernel_launch(void* const* d_in, const int* in_sizes, int n_in,
                              void* d_out, int out_size, void* d_ws, size_t ws_size,
                              hipStream_t stream)
{
    const int*   input_ids      = (const int*)  d_in[0];
    const int*   segment_ids    = (const int*)  d_in[1];
    const float* attention_mask = (const float*)d_in[2];
    const float* tok_emb = (const float*)d_in[3];
    const float* pos_emb = (const float*)d_in[4];
    const float* type_emb= (const float*)d_in[5];
    const float* emb_g   = (const float*)d_in[6];
    const float* emb_b   = (const float*)d_in[7];
    const float* Wq  = (const float*)d_in[8];  const float* bq  = (const float*)d_in[9];
    const float* Wk  = (const float*)d_in[10]; const float* bk  = (const float*)d_in[11];
    const float* Wv  = (const float*)d_in[12]; const float* bv  = (const float*)d_in[13];
    const float* Wao = (const float*)d_in[14]; const float* bao = (const float*)d_in[15];
    const float* ln1_g = (const float*)d_in[16]; const float* ln1_b = (const float*)d_in[17];
    const float* Wi  = (const float*)d_in[18]; const float* bi  = (const float*)d_in[19];
    const float* Wio = (const float*)d_in[20]; const float* bio = (const float*)d_in[21];
    const float* ln2_g = (const float*)d_in[22]; const float* ln2_b = (const float*)d_in[23];

    float* out = (float*)d_out;

    const size_t NT = (size_t)NTOK * Hc;
    float* BALL = (float*)d_ws;                              // 12*2304 fp32
    unsigned short* QKb = (unsigned short*)(BALL + (size_t)Lc * QKVN);
    unsigned short* VT  = QKb + (size_t)NTOK * 1536;         // [B][NH][DH][S]
    unsigned short* Xb  = VT + NT;                           // residual/GEMM-in (fp16)
    unsigned short* XAb = Xb + NT;
    unsigned short* Cb  = XAb + NT;
    unsigned short* Tp  = Cb + NT;                           // 2 x NT fp16 split-K partials
    unsigned short* Hb  = Tp + 2 * NT;                       // [NTOK][3072]
    unsigned short* WALL = Hb + (size_t)NTOK * Fc;           // 12 * LW fp16 (tiled)

    // ---- one-shot prep: all weight transposes + bias concat ----
    prep_kernel<<<dim3(1737, Lc), 256, 0, stream>>>(Wq, Wk, Wv, Wao, Wi, Wio,
                                                    bq, bk, bv, WALL, BALL);

    embed_ln_kernel<<<NTOK, 192, 0, stream>>>(input_ids, segment_ids, tok_emb,
                                              type_emb, pos_emb, emb_g, emb_b, Xb);

    dim3 gQKV(NTOK / 128, QKVN / 128);      // 32 x 18
    dim3 gF(NTOK / 128, Fc / 128);          // 32 x 24
    dim3 gH2(NTOK / 128, Hc / 128, 2);      // 32 x 6 x 2 (split-K AO/FFN2)
    dim3 gA(Sc / 64, NHc, Bc);              // 8 x 12 x 8

    for (int l = 0; l < Lc; l++) {
        const unsigned short* WqkvT = WALL + (size_t)l * LW + W_QKV_OFF;
        const unsigned short* WaoT  = WALL + (size_t)l * LW + W_AO_OFF;
        const unsigned short* WiT   = WALL + (size_t)l * LW + W_I_OFF;
        const unsigned short* WioT  = WALL + (size_t)l * LW + W_IO_OFF;
        const float* bqkv = BALL + (size_t)l * QKVN;

        // fused QKV GEMM -> QKb (Q,K) + VT (V transposed)
        gemm_mfma<3><<<gQKV, 256, 0, stream>>>(Xb, WqkvT, bqkv, QKb, VT,
                                               NTOK, QKVN, Hc, Hc);
        attn_mfma<<<gA, 256, 0, stream>>>(QKb, VT, attention_mask, Cb);

        // attention-out dense, split-K=2 -> fp16 partials
        gemm_mfma<4><<<gH2, 256, 0, stream>>>(Cb, WaoT, bao + (size_t)l * Hc, Tp,
                                              nullptr, NTOK, Hc, Hc, Hc / 2);
        // LN(T + X) -> XAb (fp16)
        add_ln2h_kernel<<<NTOK, 192, 0, stream>>>(Tp, Tp + NT, Xb,
                                                  ln1_g + (size_t)l * Hc,
                                                  ln1_b + (size_t)l * Hc, XAb, nullptr);

        // FFN1 + gelu -> Hb (fp16)
        gemm_mfma<1><<<gF, 256, 0, stream>>>(XAb, WiT, bi + (size_t)l * Fc, Hb,
                                             nullptr, NTOK, Fc, Hc, Hc);
        // FFN2 split-K=2 -> fp16 partials
        gemm_mfma<4><<<gH2, 256, 0, stream>>>(Hb, WioT, bio + (size_t)l * Hc, Tp,
                                              nullptr, NTOK, Hc, Fc, Fc / 2);
        // LN(T2 + XA) -> Xb (fp16); final layer also writes fp32 out
        add_ln2h_kernel<<<NTOK, 192, 0, stream>>>(Tp, Tp + NT, XAb,
                                                  ln2_g + (size_t)l * Hc,
                                                  ln2_b + (size_t)l * Hc, Xb,
                                                  (l == Lc - 1) ? out : nullptr);
    }
}

// Round 15
// 1949.983 us; speedup vs baseline: 1.1328x; 1.0017x over previous
//
#include <hip/hip_runtime.h>
#include <math.h>

// Problem constants
static constexpr int Bc = 8;
static constexpr int Sc = 512;
static constexpr int Hc = 768;
static constexpr int NHc = 12;
static constexpr int Lc = 12;
static constexpr int Fc = 3072;
static constexpr int DHc = 64;
static constexpr int NTOK = Bc * Sc;      // 4096
static constexpr int QKVN = 3 * Hc;       // 2304

// all-layer transposed-weight block offsets (fp16 elements).
// Weights are stored TILED: [N/128][K/64][128][64] (tile = 8192 elems),
// matching exactly what one GEMM block stages per K-step.
static constexpr size_t W_QKV_OFF = 0;                    // 216 tiles
static constexpr size_t W_AO_OFF  = 1769472;              // 72 tiles
static constexpr size_t W_I_OFF   = 2359296;              // 288 tiles
static constexpr size_t W_IO_OFF  = 4718592;              // 288 tiles
static constexpr size_t LW        = 7077888;              // per-layer total

typedef _Float16 h16x8 __attribute__((ext_vector_type(8)));
typedef float f32x4 __attribute__((ext_vector_type(4)));
typedef unsigned short us4 __attribute__((ext_vector_type(4)));
typedef unsigned short us8 __attribute__((ext_vector_type(8)));
typedef unsigned int u32x4 __attribute__((ext_vector_type(4)));

__device__ __forceinline__ unsigned short f2h(float f) {
    _Float16 h = (_Float16)f;                    // v_cvt_f16_f32, RTE
    return __builtin_bit_cast(unsigned short, h);
}
__device__ __forceinline__ float h2f(unsigned short u) {
    return (float)__builtin_bit_cast(_Float16, u);
}

#define AS1 __attribute__((address_space(1)))
#define AS3 __attribute__((address_space(3)))
__device__ __forceinline__ void gld_lds16(const void* g, void* l) {
    __builtin_amdgcn_global_load_lds((const AS1 void*)g, (AS3 void*)l, 16, 0, 0);
}

// ---------------------------------------------------------------------------
// ALL-layer weight prep: 64x64 transpose tiles, float4 reads, us8 writes to
// the TILED layout (sequential 8 KB stream per block). ~127 us, 4.0 TB/s
// effective (510 real MB) -- accepted as prep's practical ceiling.
// blockIdx.y = layer; blockIdx.x: 1728 tiles + 9 bias blocks.
// ---------------------------------------------------------------------------
__global__ __launch_bounds__(256) void prep_kernel(
    const float* __restrict__ Wq, const float* __restrict__ Wk,
    const float* __restrict__ Wv, const float* __restrict__ Wao,
    const float* __restrict__ Wi, const float* __restrict__ Wio,
    const float* __restrict__ bq, const float* __restrict__ bk,
    const float* __restrict__ bv, unsigned short* __restrict__ WALL,
    float* __restrict__ BALL)
{
    int t = blockIdx.x, l = blockIdx.y;
    int tid = threadIdx.x;

    if (t >= 1728) {   // bias concat: 9 blocks x 256 = 2304
        int idx = (t - 1728) * 256 + tid;
        float v = (idx < 768) ? bq[l * Hc + idx]
                : (idx < 1536) ? bk[l * Hc + idx - 768]
                               : bv[l * Hc + idx - 1536];
        BALL[(size_t)l * QKVN + idx] = v;
        return;
    }

    const float* src;
    unsigned short* dst;
    int K, N, ntn, local;
    if (t < 576) {                       // Wq,Wk,Wv,Wao: 144 tiles each
        int mat = t / 144; local = t % 144;
        K = 768; N = 768; ntn = 12;
        src = (mat == 0 ? Wq : mat == 1 ? Wk : mat == 2 ? Wv : Wao) + (size_t)l * 589824;
        dst = WALL + (size_t)l * LW + (mat < 3 ? (size_t)mat * 589824 : W_AO_OFF);
    } else if (t < 1152) {               // Wi: 576 tiles
        local = t - 576; K = 768; N = 3072; ntn = 48;
        src = Wi + (size_t)l * 2359296;
        dst = WALL + (size_t)l * LW + W_I_OFF;
    } else {                             // Wio: 576 tiles
        local = t - 1152; K = 3072; N = 768; ntn = 12;
        src = Wio + (size_t)l * 2359296;
        dst = WALL + (size_t)l * LW + W_IO_OFF;
    }
    int n0 = (local % ntn) * 64, k0 = (local / ntn) * 64;

    // tiled dst: tile (n0>>7, k0>>6), half-tile select on bit 6 of n0
    int nkt = K >> 6;
    unsigned short* dstb = dst + ((size_t)(n0 >> 7) * nkt + (k0 >> 6)) * 8192
                               + ((n0 >> 6) & 1) * 4096;

    __shared__ float tl[64][65];
    int tx = tid & 15, ty = tid >> 4;    // tx: 4-float col group, ty: row
#pragma unroll
    for (int j = 0; j < 4; j++) {
        int k = ty + j * 16;
        float4 v = *(const float4*)(src + (size_t)(k0 + k) * N + n0 + tx * 4);
        tl[k][tx * 4 + 0] = v.x; tl[k][tx * 4 + 1] = v.y;
        tl[k][tx * 4 + 2] = v.z; tl[k][tx * 4 + 3] = v.w;
    }
    __syncthreads();
#pragma unroll
    for (int q = 0; q < 2; q++) {
        int chunk = q * 256 + tid;
        int row = chunk >> 3, c = chunk & 7;
        us8 o;
#pragma unroll
        for (int j = 0; j < 8; j++) o[j] = f2h(tl[c * 8 + j][row]);
        *(us8*)(dstb + (size_t)chunk * 8) = o;   // sequential stream
    }
}

// ---------------------------------------------------------------------------
// 192-thread LN reduction helper: thread i owns elems 4i..4i+3 of a 768-row.
// ---------------------------------------------------------------------------
__device__ __forceinline__ void ln_stats192(float4 v, float& mean, float& rstd) {
    float s = v.x + v.y + v.z + v.w;
    float s2 = v.x * v.x + v.y * v.y + v.z * v.z + v.w * v.w;
#pragma unroll
    for (int o = 32; o > 0; o >>= 1) { s += __shfl_xor(s, o); s2 += __shfl_xor(s2, o); }
    __shared__ float red[6];
    int lane = threadIdx.x & 63, wid = threadIdx.x >> 6;
    if (lane == 0) { red[wid] = s; red[3 + wid] = s2; }
    __syncthreads();
    float ts  = red[0] + red[1] + red[2];
    float ts2 = red[3] + red[4] + red[5];
    mean = ts * (1.0f / Hc);
    float var = ts2 * (1.0f / Hc) - mean * mean;
    rstd = rsqrtf(var + 1e-12f);
}

// ---------------------------------------------------------------------------
// Embedding + LayerNorm -> fp16 X  (192 threads, float4)
// ---------------------------------------------------------------------------
__global__ __launch_bounds__(192) void embed_ln_kernel(
    const int* __restrict__ ids, const int* __restrict__ seg,
    const float* __restrict__ tok, const float* __restrict__ typ,
    const float* __restrict__ pos, const float* __restrict__ g,
    const float* __restrict__ b, unsigned short* __restrict__ outb)
{
    int t = blockIdx.x;
    int si = t % Sc;
    int id = ids[t], sg = seg[t];
    int i = threadIdx.x;

    float4 tv = *(const float4*)(tok + (size_t)id * Hc + 4 * i);
    float4 yv = *(const float4*)(typ + (size_t)sg * Hc + 4 * i);
    float4 pv = *(const float4*)(pos + (size_t)si * Hc + 4 * i);
    float4 v = make_float4(tv.x + yv.x + pv.x, tv.y + yv.y + pv.y,
                           tv.z + yv.z + pv.z, tv.w + yv.w + pv.w);
    float mean, rstd;
    ln_stats192(v, mean, rstd);

    float4 gv = *(const float4*)(g + 4 * i);
    float4 bv = *(const float4*)(b + 4 * i);
    us4 ob;
    ob[0] = f2h(gv.x * (v.x - mean) * rstd + bv.x);
    ob[1] = f2h(gv.y * (v.y - mean) * rstd + bv.y);
    ob[2] = f2h(gv.z * (v.z - mean) * rstd + bv.z);
    ob[3] = f2h(gv.w * (v.w - mean) * rstd + bv.w);
    *(us4*)(outb + (size_t)t * Hc + 4 * i) = ob;
}

// ---------------------------------------------------------------------------
// (fp16 partial0 + fp16 partial1 + fp16 residual) -> LN -> fp16
// (+ fp32 out on final layer via nullable outf)
// ---------------------------------------------------------------------------
__global__ __launch_bounds__(192) void add_ln2h_kernel(
    const unsigned short* __restrict__ t0, const unsigned short* __restrict__ t1,
    const unsigned short* __restrict__ res, const float* __restrict__ g,
    const float* __restrict__ b, unsigned short* __restrict__ outb,
    float* __restrict__ outf)
{
    int t = blockIdx.x;
    int i = threadIdx.x;
    us4 a = *(const us4*)(t0 + (size_t)t * Hc + 4 * i);
    us4 c = *(const us4*)(t1 + (size_t)t * Hc + 4 * i);
    us4 r = *(const us4*)(res + (size_t)t * Hc + 4 * i);
    float4 v = make_float4(h2f(a[0]) + h2f(c[0]) + h2f(r[0]),
                           h2f(a[1]) + h2f(c[1]) + h2f(r[1]),
                           h2f(a[2]) + h2f(c[2]) + h2f(r[2]),
                           h2f(a[3]) + h2f(c[3]) + h2f(r[3]));
    float mean, rstd;
    ln_stats192(v, mean, rstd);

    float4 gv = *(const float4*)(g + 4 * i);
    float4 bv = *(const float4*)(b + 4 * i);
    float4 o = make_float4(gv.x * (v.x - mean) * rstd + bv.x,
                           gv.y * (v.y - mean) * rstd + bv.y,
                           gv.z * (v.z - mean) * rstd + bv.z,
                           gv.w * (v.w - mean) * rstd + bv.w);
    us4 ob; ob[0] = f2h(o.x); ob[1] = f2h(o.y); ob[2] = f2h(o.z); ob[3] = f2h(o.w);
    *(us4*)(outb + (size_t)t * Hc + 4 * i) = ob;
    if (outf) *(float4*)(outf + (size_t)t * Hc + 4 * i) = o;
}

// ---------------------------------------------------------------------------
// FP16 MFMA GEMM (single-buffer m97 structure, ~4 blocks/CU) + XCD swizzle.
// B is in TILED layout [N/128][K/64][128][64] -> B staging reads are a
// contiguous 16 KB block per K-step.
// OUT: 1 = gelu+fp16, 2 = fp16, 3 = QKV mode (col<1536 -> Cb ld 1536,
//      col>=1536 -> V transposed to VTp[B][NH][DH][S]),
//      4 = fp16 split-K partial to Cb + z*M*N (bias added on z==0 only)
// ---------------------------------------------------------------------------
template <int OUT>
__global__ __launch_bounds__(256) void gemm_mfma(
    const unsigned short* __restrict__ A,   // [M][K] fp16
    const unsigned short* __restrict__ Bt,  // tiled fp16
    const float* __restrict__ bias,         // [N]
    unsigned short* __restrict__ Cb,
    unsigned short* __restrict__ VTp,
    int M, int N, int K, int kspan)
{
    __shared__ __align__(16) unsigned short As[128 * 64];
    __shared__ __align__(16) unsigned short Bs[128 * 64];

    int tid = threadIdx.x;
    int l = tid & 63, w = tid >> 6;

    // XCD-aware swizzle (bijective: all grids here have nwg % 8 == 0)
    int nbx = gridDim.x;
    int nwg = nbx * gridDim.y;
    int bid = blockIdx.y * nbx + blockIdx.x;
    if ((nwg & 7) == 0) {
        int cpx = nwg >> 3;
        bid = (bid & 7) * cpx + (bid >> 3);
    }
    int m0 = (bid % nbx) * 128, n0 = (bid / nbx) * 128;

    int lr = l & 15;
    int kg = l >> 4;
    int wr = (w >> 1) * 64, wc = (w & 1) * 64;
    int lx = lr & 7;
    int kbeg = blockIdx.z * kspan;
    int nkt = K >> 6;
    const unsigned short* BtRow = Bt + (size_t)(n0 >> 7) * nkt * 8192;

    f32x4 acc[4][4] = {};

    for (int k0 = kbeg; k0 < kbeg + kspan; k0 += 64) {
        const unsigned short* gbBase = BtRow + (size_t)(k0 >> 6) * 8192;
#pragma unroll
        for (int p = 0; p < 4; p++) {
            int i = p * 256 + w * 64 + l;
            int row = i >> 3;
            int slot = (i & 7) ^ (row & 7);
            const unsigned short* ga = A + (size_t)(m0 + row) * K + k0 + slot * 8;
            const unsigned short* gb = gbBase + row * 64 + slot * 8;
            unsigned short* la = As + (size_t)(p * 256 + w * 64) * 8;
            unsigned short* lb = Bs + (size_t)(p * 256 + w * 64) * 8;
            gld_lds16(ga, la);
            gld_lds16(gb, lb);
        }
        asm volatile("s_waitcnt vmcnt(0)" ::: "memory");
        __syncthreads();

#pragma unroll
        for (int kh = 0; kh < 2; kh++) {
            h16x8 av[4], bv[4];
#pragma unroll
            for (int f = 0; f < 4; f++) {
                int sl = (kh * 4 + kg) ^ lx;
                av[f] = *(const h16x8*)(As + (wr + f * 16 + lr) * 64 + sl * 8);
                bv[f] = *(const h16x8*)(Bs + (wc + f * 16 + lr) * 64 + sl * 8);
            }
#pragma unroll
            for (int i = 0; i < 4; i++)
#pragma unroll
                for (int j = 0; j < 4; j++)
                    acc[i][j] = __builtin_amdgcn_mfma_f32_16x16x32_f16(
                        av[i], bv[j], acc[i][j], 0, 0, 0);
        }
        __syncthreads();
    }

#pragma unroll
    for (int i = 0; i < 4; i++) {
        int rbase = m0 + wr + i * 16 + kg * 4;
#pragma unroll
        for (int j = 0; j < 4; j++) {
            int col = n0 + wc + j * 16 + lr;
            float bcol = (OUT == 4 && blockIdx.z > 0) ? 0.f : bias[col];
            if (OUT == 3 && col >= 1536) {
                // V columns -> transposed store VT[b][h][d][s]
                int vcol = col - 1536;
                int hh = vcol >> 6, d = vcol & 63;
                int bbb = rbase >> 9, s0 = rbase & 511;
                us4 ob;
#pragma unroll
                for (int r = 0; r < 4; r++) ob[r] = f2h(acc[i][j][r] + bcol);
                *(us4*)(VTp + ((((size_t)bbb * NHc + hh) * DHc + d) << 9) + s0) = ob;
            } else if (OUT == 4) {
                unsigned short* op = Cb + (size_t)blockIdx.z * M * N;
#pragma unroll
                for (int r = 0; r < 4; r++)
                    op[(size_t)(rbase + r) * N + col] = f2h(acc[i][j][r] + bcol);
            } else {
                int ldc = (OUT == 3) ? 1536 : N;
#pragma unroll
                for (int r = 0; r < 4; r++) {
                    float v = acc[i][j][r] + bcol;
                    if (OUT == 1) v = 0.5f * v * (1.0f + erff(v * 0.70710678118654752f));
                    Cb[(size_t)(rbase + r) * ldc + col] = f2h(v);
                }
            }
        }
    }
}

// ---------------------------------------------------------------------------
// MFMA flash attention, Q-tile=128 (8 waves, 512 threads). Per-wave math,
// LDS layout (16.5 KB), swizzles, and PV shuffle identical to the verified
// KVBLK=64 kernel; waves 0..7 each own 16 q-rows. K/V staging halves per
// q-row (one gld_lds16 pass per tile), block barriers halve. Occupancy
// unchanged: 4 blocks/CU x 8 waves = 32 waves/CU.
// QK fp16 [NTOK][1536] (Q at 0, K at 768); VT fp16 [B][NH][DH][S].
// Out ctx fp16 [NTOK][768].
// ---------------------------------------------------------------------------
__global__ __launch_bounds__(512) void attn_mfma(
    const unsigned short* __restrict__ QK, const unsigned short* __restrict__ VT,
    const float* __restrict__ mask, unsigned short* __restrict__ O)
{
    const int LD = 1536;
    __shared__ __align__(16) unsigned short Ks[64 * 64];
    __shared__ __align__(16) unsigned short Vt[64 * 64];   // [d][kv], swizzled
    __shared__ float Ml[64];

    int tid = threadIdx.x;
    int l = tid & 63, w = tid >> 6;      // w: 0..7
    int g = l >> 4, c = l & 15;
    int q0 = blockIdx.x * 128;
    int h = blockIdx.y, bb = blockIdx.z;

    // Q fragment (B-operand of S^T mfma): Q[q=c][d = 32*kh + 8g + j]
    const size_t rowQ = (size_t)(bb * Sc + q0 + w * 16 + c) * LD + h * DHc;
    h16x8 qv[2];
    qv[0] = *(const h16x8*)(QK + rowQ + 8 * g);
    qv[1] = *(const h16x8*)(QK + rowQ + 32 + 8 * g);

    float m_run = -1e30f, l_run = 0.f;
    f32x4 acc_o[4] = {};
    const float scale = 0.125f;

    for (int kt = 0; kt < Sc; kt += 64) {
        // ---- stage K tile: 512 thr x 16B = 8 KB in one pass ----
        const unsigned short* Kgb = QK + (size_t)(bb * Sc + kt) * LD + Hc + h * DHc;
        {
            int i = tid;
            int row = i >> 3;
            int slot = (i & 7) ^ (row & 7);
            gld_lds16(Kgb + (size_t)row * LD + slot * 8, Ks + (size_t)(w * 64) * 8);
        }
        // ---- stage V^T tile from VT[b][h][d][s] ----
        const unsigned short* Vg = VT + (((size_t)bb * NHc + h) * DHc << 9) + kt;
        {
            int i = tid;
            int row = i >> 3;
            int slot = (i & 7) ^ (row & 7);
            gld_lds16(Vg + ((size_t)row << 9) + slot * 8, Vt + (size_t)(w * 64) * 8);
        }
        if (tid < 64) Ml[tid] = (1.0f - mask[bb * Sc + kt + tid]) * -10000.0f;
        asm volatile("s_waitcnt vmcnt(0)" ::: "memory");
        __syncthreads();

        // ---- S^T = K @ Q^T : rows kv (4 frags), cols q ----
        f32x4 s[4] = {};
#pragma unroll
        for (int kh = 0; kh < 2; kh++) {
#pragma unroll
            for (int f = 0; f < 4; f++) {
                int row = f * 16 + c;
                h16x8 av = *(const h16x8*)(Ks + row * 64 + (((kh * 4 + g) ^ (row & 7)) * 8));
                s[f] = __builtin_amdgcn_mfma_f32_16x16x32_f16(av, qv[kh], s[f], 0, 0, 0);
            }
        }

        // ---- softmax (per q = c, values spread over g-groups) ----
        f32x4 mv[4];
#pragma unroll
        for (int f = 0; f < 4; f++) mv[f] = *(const f32x4*)&Ml[f * 16 + 4 * g];
        float mx = -1e30f;
#pragma unroll
        for (int f = 0; f < 4; f++)
#pragma unroll
            for (int r = 0; r < 4; r++) {
                float sv = s[f][r] * scale + mv[f][r];
                s[f][r] = sv;
                mx = fmaxf(mx, sv);
            }
        mx = fmaxf(mx, __shfl_xor(mx, 16));
        mx = fmaxf(mx, __shfl_xor(mx, 32));
        float mn = fmaxf(m_run, mx);
        float fs = __expf(m_run - mn);
        m_run = mn;
        float ps = 0.f;
        f32x4 p[4];
#pragma unroll
        for (int f = 0; f < 4; f++)
#pragma unroll
            for (int r = 0; r < 4; r++) {
                float pv = __expf(s[f][r] - mn);
                p[f][r] = pv;
                ps += pv;
            }
        ps += __shfl_xor(ps, 16);
        ps += __shfl_xor(ps, 32);
        l_run = l_run * fs + ps;
#pragma unroll
        for (int fm = 0; fm < 4; fm++)
#pragma unroll
            for (int r = 0; r < 4; r++) acc_o[fm][r] *= fs;

        // ---- pack P to fp16 pairs ----
        unsigned pk[4][2];
#pragma unroll
        for (int f = 0; f < 4; f++)
#pragma unroll
            for (int rp = 0; rp < 2; rp++)
                pk[f][rp] = ((unsigned)f2h(p[f][2 * rp + 1]) << 16) | f2h(p[f][2 * rp]);

        // ---- PV: O^T += Vt @ P^T ----
        // dest lane (g,c) word t needs P[q=c][kv=32kh+8g+2t+{0,1}] =
        // pk[2kh + (g>>1)][t&1] from lane g_src = 2(g&1)+(t>>1);
        // f-select AFTER shuffle (uses dest g).
#pragma unroll
        for (int kh = 0; kh < 2; kh++) {
            u32x4 bw;
#pragma unroll
            for (int t = 0; t < 4; t++) {
                int srcl = (2 * ((l >> 4) & 1) + (t >> 1)) * 16 + c;
                unsigned lo = __shfl(pk[2 * kh][t & 1], srcl);
                unsigned hi = __shfl(pk[2 * kh + 1][t & 1], srcl);
                bw[t] = (g & 2) ? hi : lo;
            }
            h16x8 bfrag = __builtin_bit_cast(h16x8, bw);
#pragma unroll
            for (int fm = 0; fm < 4; fm++) {
                int row = fm * 16 + c;
                h16x8 av = *(const h16x8*)(Vt + row * 64 + (((kh * 4 + g) ^ (row & 7)) * 8));
                acc_o[fm] = __builtin_amdgcn_mfma_f32_16x16x32_f16(av, bfrag, acc_o[fm], 0, 0, 0);
            }
        }
        __syncthreads();
    }

    // ---- epilogue: O[q=c][d = 16fm + 4g + r] / l ----
    float rl = 1.0f / l_run;
    size_t tokrow = (size_t)(bb * Sc + q0 + w * 16 + c) * Hc + h * DHc;
#pragma unroll
    for (int fm = 0; fm < 4; fm++) {
        us4 ob;
#pragma unroll
        for (int r = 0; r < 4; r++) ob[r] = f2h(acc_o[fm][r] * rl);
        *(us4*)(O + tokrow + fm * 16 + 4 * g) = ob;
    }
}

// ---------------------------------------------------------------------------
extern "C" void kernel_launch(void* const* d_in, const int* in_sizes, int n_in,
                              void* d_out, int out_size, void* d_ws, size_t ws_size,
                              hipStream_t stream)
{
    const int*   input_ids      = (const int*)  d_in[0];
    const int*   segment_ids    = (const int*)  d_in[1];
    const float* attention_mask = (const float*)d_in[2];
    const float* tok_emb = (const float*)d_in[3];
    const float* pos_emb = (const float*)d_in[4];
    const float* type_emb= (const float*)d_in[5];
    const float* emb_g   = (const float*)d_in[6];
    const float* emb_b   = (const float*)d_in[7];
    const float* Wq  = (const float*)d_in[8];  const float* bq  = (const float*)d_in[9];
    const float* Wk  = (const float*)d_in[10]; const float* bk  = (const float*)d_in[11];
    const float* Wv  = (const float*)d_in[12]; const float* bv  = (const float*)d_in[13];
    const float* Wao = (const float*)d_in[14]; const float* bao = (const float*)d_in[15];
    const float* ln1_g = (const float*)d_in[16]; const float* ln1_b = (const float*)d_in[17];
    const float* Wi  = (const float*)d_in[18]; const float* bi  = (const float*)d_in[19];
    const float* Wio = (const float*)d_in[20]; const float* bio = (const float*)d_in[21];
    const float* ln2_g = (const float*)d_in[22]; const float* ln2_b = (const float*)d_in[23];

    float* out = (float*)d_out;

    const size_t NT = (size_t)NTOK * Hc;
    float* BALL = (float*)d_ws;                              // 12*2304 fp32
    unsigned short* QKb = (unsigned short*)(BALL + (size_t)Lc * QKVN);
    unsigned short* VT  = QKb + (size_t)NTOK * 1536;         // [B][NH][DH][S]
    unsigned short* Xb  = VT + NT;                           // residual/GEMM-in (fp16)
    unsigned short* XAb = Xb + NT;
    unsigned short* Cb  = XAb + NT;
    unsigned short* Tp  = Cb + NT;                           // 2 x NT fp16 split-K partials
    unsigned short* Hb  = Tp + 2 * NT;                       // [NTOK][3072]
    unsigned short* WALL = Hb + (size_t)NTOK * Fc;           // 12 * LW fp16 (tiled)

    // ---- one-shot prep: all weight transposes + bias concat ----
    prep_kernel<<<dim3(1737, Lc), 256, 0, stream>>>(Wq, Wk, Wv, Wao, Wi, Wio,
                                                    bq, bk, bv, WALL, BALL);

    embed_ln_kernel<<<NTOK, 192, 0, stream>>>(input_ids, segment_ids, tok_emb,
                                              type_emb, pos_emb, emb_g, emb_b, Xb);

    dim3 gQKV(NTOK / 128, QKVN / 128);      // 32 x 18
    dim3 gF(NTOK / 128, Fc / 128);          // 32 x 24
    dim3 gH2(NTOK / 128, Hc / 128, 2);      // 32 x 6 x 2 (split-K AO/FFN2)
    dim3 gA(Sc / 128, NHc, Bc);             // 4 x 12 x 8

    for (int l = 0; l < Lc; l++) {
        const unsigned short* WqkvT = WALL + (size_t)l * LW + W_QKV_OFF;
        const unsigned short* WaoT  = WALL + (size_t)l * LW + W_AO_OFF;
        const unsigned short* WiT   = WALL + (size_t)l * LW + W_I_OFF;
        const unsigned short* WioT  = WALL + (size_t)l * LW + W_IO_OFF;
        const float* bqkv = BALL + (size_t)l * QKVN;

        // fused QKV GEMM -> QKb (Q,K) + VT (V transposed)
        gemm_mfma<3><<<gQKV, 256, 0, stream>>>(Xb, WqkvT, bqkv, QKb, VT,
                                               NTOK, QKVN, Hc, Hc);
        attn_mfma<<<gA, 512, 0, stream>>>(QKb, VT, attention_mask, Cb);

        // attention-out dense, split-K=2 -> fp16 partials
        gemm_mfma<4><<<gH2, 256, 0, stream>>>(Cb, WaoT, bao + (size_t)l * Hc, Tp,
                                              nullptr, NTOK, Hc, Hc, Hc / 2);
        // LN(T + X) -> XAb (fp16)
        add_ln2h_kernel<<<NTOK, 192, 0, stream>>>(Tp, Tp + NT, Xb,
                                                  ln1_g + (size_t)l * Hc,
                                                  ln1_b + (size_t)l * Hc, XAb, nullptr);

        // FFN1 + gelu -> Hb (fp16)
        gemm_mfma<1><<<gF, 256, 0, stream>>>(XAb, WiT, bi + (size_t)l * Fc, Hb,
                                             nullptr, NTOK, Fc, Hc, Hc);
        // FFN2 split-K=2 -> fp16 partials
        gemm_mfma<4><<<gH2, 256, 0, stream>>>(Hb, WioT, bio + (size_t)l * Hc, Tp,
                                              nullptr, NTOK, Hc, Fc, Fc / 2);
        // LN(T2 + XA) -> Xb (fp16); final layer also writes fp32 out
        add_ln2h_kernel<<<NTOK, 192, 0, stream>>>(Tp, Tp + NT, XAb,
                                                  ln2_g + (size_t)l * Hc,
                                                  ln2_b + (size_t)l * Hc, Xb,
                                                  (l == Lc - 1) ? out : nullptr);
    }
}